// Round 1
// baseline (640.478 us; speedup 1.0000x reference)
//
#include <hip/hip_runtime.h>

#define EMBED 768
#define FFDIM 1536
#define BATCH 4
#define SEQ   2048
#define HEADS 12
#define MROWS (BATCH*SEQ)   // 8192

typedef __attribute__((ext_vector_type(4))) float  f32x4;
typedef __attribute__((ext_vector_type(8))) __bf16 bf16x8;
typedef __attribute__((ext_vector_type(4))) short  s16x4;

__device__ __forceinline__ short f2bf(float f) {
    union { float f; unsigned u; } x; x.f = f;
    unsigned r = x.u + 0x7fffu + ((x.u >> 16) & 1u);
    return (short)(r >> 16);
}

__device__ __forceinline__ void gll16(const void* g, void* l) {
    __builtin_amdgcn_global_load_lds(
        (const __attribute__((address_space(1))) void*)g,
        (__attribute__((address_space(3))) void*)l, 16, 0, 0);
}

// ---------------- fp32 -> bf16 convert (4 tensors, same size) ----------------
__global__ __launch_bounds__(256) void cvt4_kernel(
    const float* __restrict__ s0, const float* __restrict__ s1,
    const float* __restrict__ s2, const float* __restrict__ s3,
    short* __restrict__ o0, short* __restrict__ o1,
    short* __restrict__ o2, short* __restrict__ o3)
{
    const float* s; short* o;
    switch (blockIdx.y) {
        case 0:  s = s0; o = o0; break;
        case 1:  s = s1; o = o1; break;
        case 2:  s = s2; o = o2; break;
        default: s = s3; o = o3; break;
    }
    size_t i = ((size_t)blockIdx.x * 256 + threadIdx.x) * 4;
    float4 v = *(const float4*)(s + i);
    s16x4 r;
    r[0] = f2bf(v.x); r[1] = f2bf(v.y); r[2] = f2bf(v.z); r[3] = f2bf(v.w);
    *(s16x4*)(o + i) = r;
}

// ---------------- weight transpose+convert: W[K][N] f32 -> Wt[N][K] bf16 ----------------
__global__ __launch_bounds__(256) void transpose_w(
    const float* __restrict__ W, short* __restrict__ Wt, int K, int N)
{
    __shared__ float tile[32][33];
    const int k0 = blockIdx.y * 32, n0 = blockIdx.x * 32;
    const int tx = threadIdx.x & 31, ty = threadIdx.x >> 5;  // 32 x 8
    #pragma unroll
    for (int i = 0; i < 32; i += 8)
        tile[ty + i][tx] = W[(size_t)(k0 + ty + i) * N + n0 + tx];
    __syncthreads();
    #pragma unroll
    for (int i = 0; i < 32; i += 8)
        Wt[(size_t)(n0 + ty + i) * K + k0 + tx] = f2bf(tile[tx][ty + i]);
}

// ---------------- v [B*SEQ][768] bf16 -> vt [B][H][64][SEQ] bf16 ----------------
__global__ __launch_bounds__(256) void transpose_v(
    const short* __restrict__ v, short* __restrict__ vt)
{
    __shared__ short tile[64][65];
    const int bh = blockIdx.y;
    const int b = bh / HEADS, h = bh % HEADS;
    const int k0 = blockIdx.x * 64;
    const int tx = threadIdx.x & 63, ty = threadIdx.x >> 6;  // 64 x 4
    #pragma unroll
    for (int i = 0; i < 64; i += 4)
        tile[ty + i][tx] = v[(size_t)(b * SEQ + k0 + ty + i) * EMBED + h * 64 + tx];
    __syncthreads();
    #pragma unroll
    for (int i = 0; i < 64; i += 4)
        vt[(size_t)(bh * 64 + ty + i) * SEQ + k0 + tx] = tile[tx][ty + i];
}

// ---------------- GEMM: out = act(A[M][K] @ Wt[N][K]^T + bias (+resid)) ----------------
// 128x128 tile, BK=32, 4 waves (2x2), each wave 64x64 out via 4x4 16x16x32 MFMAs.
template<int L2N, int GELU_, int RES, int SBF, int SF32>
__global__ __launch_bounds__(256) void gemm_bt(
    const short* __restrict__ A, const short* __restrict__ Wt,
    const float* __restrict__ bias, const float* __restrict__ resid,
    short* __restrict__ outb, float* __restrict__ outf,
    int M, int N, int K)
{
    __shared__ short As[128][32];
    __shared__ short Bs[128][32];
    const int tid = threadIdx.x;
    const int mbase = blockIdx.y * 128, nbase = blockIdx.x * 128;
    const int wid = tid >> 6, lane = tid & 63;
    const int wm = wid >> 1, wn = wid & 1;
    const int l15 = lane & 15, lhi = lane >> 4;
    const int sr = tid >> 2;         // 0..63
    const int sc = (tid & 3) * 8;    // 0/8/16/24

    f32x4 acc[4][4] = {};

    const short* Ab = A  + (size_t)mbase * K;
    const short* Bb = Wt + (size_t)nbase * K;

    for (int k0 = 0; k0 < K; k0 += 32) {
        __syncthreads();
        gll16(Ab + (size_t)sr * K        + k0 + sc, &As[sr][sc]);
        gll16(Ab + (size_t)(64 + sr) * K + k0 + sc, &As[64 + sr][sc]);
        gll16(Bb + (size_t)sr * K        + k0 + sc, &Bs[sr][sc]);
        gll16(Bb + (size_t)(64 + sr) * K + k0 + sc, &Bs[64 + sr][sc]);
        __syncthreads();
        bf16x8 av[4], bv[4];
        #pragma unroll
        for (int t = 0; t < 4; ++t) {
            av[t] = *(const bf16x8*)(&As[wm * 64 + t * 16 + l15][lhi * 8]);
            bv[t] = *(const bf16x8*)(&Bs[wn * 64 + t * 16 + l15][lhi * 8]);
        }
        #pragma unroll
        for (int mt = 0; mt < 4; ++mt)
            #pragma unroll
            for (int nt = 0; nt < 4; ++nt)
                acc[mt][nt] = __builtin_amdgcn_mfma_f32_16x16x32_bf16(
                    av[mt], bv[nt], acc[mt][nt], 0, 0, 0);
    }

    #pragma unroll
    for (int mt = 0; mt < 4; ++mt) {
        float vals[4][4];
        #pragma unroll
        for (int nt = 0; nt < 4; ++nt) {
            const int col = nbase + wn * 64 + nt * 16 + l15;
            const float bc = bias[col];
            #pragma unroll
            for (int j = 0; j < 4; ++j) vals[nt][j] = acc[mt][nt][j] + bc;
        }
        if (RES) {
            #pragma unroll
            for (int nt = 0; nt < 4; ++nt) {
                const int col = nbase + wn * 64 + nt * 16 + l15;
                #pragma unroll
                for (int j = 0; j < 4; ++j) {
                    const int row = mbase + wm * 64 + mt * 16 + lhi * 4 + j;
                    vals[nt][j] += resid[(size_t)row * N + col];
                }
            }
        }
        if (L2N) {  // l2-normalize over this wave's 64-col head span
            #pragma unroll
            for (int j = 0; j < 4; ++j) {
                float s = 0.f;
                #pragma unroll
                for (int nt = 0; nt < 4; ++nt) s += vals[nt][j] * vals[nt][j];
                s += __shfl_xor(s, 1); s += __shfl_xor(s, 2);
                s += __shfl_xor(s, 4); s += __shfl_xor(s, 8);
                const float inv = 1.0f / fmaxf(sqrtf(s), 1e-12f);
                #pragma unroll
                for (int nt = 0; nt < 4; ++nt) vals[nt][j] *= inv;
            }
        }
        if (GELU_) {
            #pragma unroll
            for (int nt = 0; nt < 4; ++nt)
                #pragma unroll
                for (int j = 0; j < 4; ++j) {
                    const float v = vals[nt][j];
                    vals[nt][j] = 0.5f * v * (1.0f + erff(v * 0.70710678118654752f));
                }
        }
        #pragma unroll
        for (int nt = 0; nt < 4; ++nt) {
            const int col = nbase + wn * 64 + nt * 16 + l15;
            #pragma unroll
            for (int j = 0; j < 4; ++j) {
                const int row = mbase + wm * 64 + mt * 16 + lhi * 4 + j;
                if (SBF)  outb[(size_t)row * N + col] = f2bf(vals[nt][j]);
                if (SF32) outf[(size_t)row * N + col] = vals[nt][j];
            }
        }
    }
}

// ---------------- attention: scores bounded in [-1,1] -> one-pass exp-sum ----------------
// grid (SEQ/64, B*H); 256 threads = 4 waves; each wave owns 16 q rows.
__global__ __launch_bounds__(256) void attn_kernel(
    const short* __restrict__ qn, const short* __restrict__ kn,
    const short* __restrict__ vt, short* __restrict__ outp)
{
    __shared__ short Qs[64][64];
    __shared__ short Ks[64][64];
    __shared__ short Vs[64][64];   // Vs[d][k]
    __shared__ short Ps[64][64];   // P rows per wave

    const int bh = blockIdx.y;
    const int b = bh / HEADS, h = bh % HEADS;
    const int q0 = blockIdx.x * 64;
    const int tid = threadIdx.x, wid = tid >> 6, lane = tid & 63;
    const int l15 = lane & 15, lhi = lane >> 4;
    const int sr = tid >> 3;          // 0..31
    const int sc = (tid & 7) * 8;     // 0..56

    // stage Q once (drained by the first __syncthreads in the loop)
    #pragma unroll
    for (int p = 0; p < 2; ++p) {
        const int r = p * 32 + sr;
        gll16(qn + (size_t)(b * SEQ + q0 + r) * EMBED + h * 64 + sc, &Qs[r][sc]);
    }

    f32x4 acc_o[4] = {};
    float rowsum[4] = {0.f, 0.f, 0.f, 0.f};

    for (int kt = 0; kt < SEQ / 64; ++kt) {
        const int k0 = kt * 64;
        __syncthreads();
        #pragma unroll
        for (int p = 0; p < 2; ++p) {
            const int r = p * 32 + sr;
            gll16(kn + (size_t)(b * SEQ + k0 + r) * EMBED + h * 64 + sc, &Ks[r][sc]);
            gll16(vt + (size_t)(bh * 64 + r) * SEQ + k0 + sc, &Vs[r][sc]);
        }
        __syncthreads();

        // S = Q K^T (this wave's 16 q rows x 64 k cols), then P = exp(S)
        bf16x8 aq0 = *(const bf16x8*)(&Qs[wid * 16 + l15][lhi * 8]);
        bf16x8 aq1 = *(const bf16x8*)(&Qs[wid * 16 + l15][32 + lhi * 8]);
        #pragma unroll
        for (int nt = 0; nt < 4; ++nt) {
            bf16x8 bk0 = *(const bf16x8*)(&Ks[nt * 16 + l15][lhi * 8]);
            bf16x8 bk1 = *(const bf16x8*)(&Ks[nt * 16 + l15][32 + lhi * 8]);
            f32x4 s = {0.f, 0.f, 0.f, 0.f};
            s = __builtin_amdgcn_mfma_f32_16x16x32_bf16(aq0, bk0, s, 0, 0, 0);
            s = __builtin_amdgcn_mfma_f32_16x16x32_bf16(aq1, bk1, s, 0, 0, 0);
            #pragma unroll
            for (int j = 0; j < 4; ++j) {
                const float e = __expf(s[j]);
                rowsum[j] += e;
                Ps[wid * 16 + lhi * 4 + j][nt * 16 + l15] = f2bf(e);
            }
        }
        __syncthreads();  // P visible across lanes

        // O += P V  (P: 16q x 64k, V: 64k x 64d via Vs[d][k])
        #pragma unroll
        for (int ks = 0; ks < 2; ++ks) {
            bf16x8 ap = *(const bf16x8*)(&Ps[wid * 16 + l15][ks * 32 + lhi * 8]);
            #pragma unroll
            for (int dt = 0; dt < 4; ++dt) {
                bf16x8 bvv = *(const bf16x8*)(&Vs[dt * 16 + l15][ks * 32 + lhi * 8]);
                acc_o[dt] = __builtin_amdgcn_mfma_f32_16x16x32_bf16(ap, bvv, acc_o[dt], 0, 0, 0);
            }
        }
    }

    // reduce rowsum across the 16-lane group (cols of S live across l15)
    #pragma unroll
    for (int j = 0; j < 4; ++j) {
        float s = rowsum[j];
        s += __shfl_xor(s, 1); s += __shfl_xor(s, 2);
        s += __shfl_xor(s, 4); s += __shfl_xor(s, 8);
        rowsum[j] = s;
    }

    #pragma unroll
    for (int dt = 0; dt < 4; ++dt)
        #pragma unroll
        for (int j = 0; j < 4; ++j) {
            const int row = q0 + wid * 16 + lhi * 4 + j;
            const int col = h * 64 + dt * 16 + l15;
            outp[(size_t)(b * SEQ + row) * EMBED + col] = f2bf(acc_o[dt][j] / rowsum[j]);
        }
}

// ---------------- layernorm over 768 cols ----------------
template<int SBF>
__global__ __launch_bounds__(256) void layernorm_768(
    const float* __restrict__ x, const float* __restrict__ g, const float* __restrict__ bb,
    float* __restrict__ outf, short* __restrict__ outb)
{
    const int row = blockIdx.x;
    const float* xr = x + (size_t)row * EMBED;
    const int t = threadIdx.x;
    const float v0 = xr[t], v1 = xr[t + 256], v2 = xr[t + 512];
    float s = v0 + v1 + v2;
    #pragma unroll
    for (int m = 1; m < 64; m <<= 1) s += __shfl_xor(s, m);
    __shared__ float red[4];
    __shared__ float red2[4];
    const int wid = t >> 6, lane = t & 63;
    if (lane == 0) red[wid] = s;
    __syncthreads();
    const float mu = (red[0] + red[1] + red[2] + red[3]) * (1.0f / 768.0f);
    const float d0 = v0 - mu, d1 = v1 - mu, d2 = v2 - mu;
    float ss = d0 * d0 + d1 * d1 + d2 * d2;
    #pragma unroll
    for (int m = 1; m < 64; m <<= 1) ss += __shfl_xor(ss, m);
    if (lane == 0) red2[wid] = ss;
    __syncthreads();
    const float var = (red2[0] + red2[1] + red2[2] + red2[3]) * (1.0f / 768.0f);
    const float inv = rsqrtf(var + 1e-5f);
    const float y0 = d0 * inv * g[t] + bb[t];
    const float y1 = d1 * inv * g[t + 256] + bb[t + 256];
    const float y2 = d2 * inv * g[t + 512] + bb[t + 512];
    float* of = outf + (size_t)row * EMBED;
    of[t] = y0; of[t + 256] = y1; of[t + 512] = y2;
    if (SBF) {
        short* ob = outb + (size_t)row * EMBED;
        ob[t] = f2bf(y0); ob[t + 256] = f2bf(y1); ob[t + 512] = f2bf(y2);
    }
}

extern "C" void kernel_launch(void* const* d_in, const int* in_sizes, int n_in,
                              void* d_out, int out_size, void* d_ws, size_t ws_size,
                              hipStream_t stream)
{
    (void)in_sizes; (void)n_in; (void)out_size; (void)ws_size;
    const float* itok = (const float*)d_in[0];
    const float* ptok = (const float*)d_in[1];
    const float* ipos = (const float*)d_in[2];
    const float* ppos = (const float*)d_in[3];
    const float* Wip = (const float*)d_in[4];  const float* bip = (const float*)d_in[5];
    const float* Wpp = (const float*)d_in[6];  const float* bpp = (const float*)d_in[7];
    const float* Wq  = (const float*)d_in[8];  const float* bq  = (const float*)d_in[9];
    const float* Wk  = (const float*)d_in[10]; const float* bk  = (const float*)d_in[11];
    const float* Wv  = (const float*)d_in[12]; const float* bv  = (const float*)d_in[13];
    const float* Wo  = (const float*)d_in[14]; const float* bo  = (const float*)d_in[15];
    const float* g1  = (const float*)d_in[16]; const float* b1  = (const float*)d_in[17];
    const float* g2  = (const float*)d_in[18]; const float* b2  = (const float*)d_in[19];
    const float* Wf1 = (const float*)d_in[20]; const float* bf1 = (const float*)d_in[21];
    const float* Wf2 = (const float*)d_in[22]; const float* bf2 = (const float*)d_in[23];
    float* out = (float*)d_out;

    char* ws = (char*)d_ws;
    constexpr size_t SZ_BF  = (size_t)MROWS * EMBED * 2;   // 12.58 MB
    constexpr size_t SZ_F32 = (size_t)MROWS * EMBED * 4;   // 25.17 MB
    constexpr size_t W768B  = (size_t)EMBED * EMBED * 2;
    constexpr size_t W1536B = (size_t)EMBED * FFDIM * 2;

    size_t o = 0;
    short* it_bf    = (short*)(ws + o); o += SZ_BF;
    short* pt_bf    = (short*)(ws + o); o += SZ_BF;
    short* ip_bf    = (short*)(ws + o); o += SZ_BF;   // reused as v_bf after G1
    short* pp_bf    = (short*)(ws + o); o += SZ_BF;   // reused as vt_bf after G2
    short* qin_bf   = (short*)(ws + o); o += SZ_BF;   // qin+kin reused as h_bf
    short* kin_bf   = (short*)(ws + o); o += SZ_BF;
    short* qn_bf    = (short*)(ws + o); o += SZ_BF;
    short* kn_bf    = (short*)(ws + o); o += SZ_BF;
    short* attn_bf  = (short*)(ws + o); o += SZ_BF;
    float* x_f32    = (float*)(ws + o); o += SZ_F32;  // x1 then x2
    short* fused_bf = (short*)(ws + o); o += SZ_BF;
    float* fused_f32= (float*)(ws + o); o += SZ_F32;
    short* wip_t = (short*)(ws + o); o += W768B;
    short* wpp_t = (short*)(ws + o); o += W768B;
    short* wq_t  = (short*)(ws + o); o += W768B;
    short* wk_t  = (short*)(ws + o); o += W768B;
    short* wv_t  = (short*)(ws + o); o += W768B;
    short* wo_t  = (short*)(ws + o); o += W768B;
    short* wf1_t = (short*)(ws + o); o += W1536B;
    short* wf2_t = (short*)(ws + o); o += W1536B;
    short* v_bf  = ip_bf;
    short* vt_bf = pp_bf;
    short* h_bf  = qin_bf;  // spans qin+kin (25.17 MB)

    const dim3 blk(256);

    cvt4_kernel<<<dim3(MROWS * EMBED / 1024, 4), blk, 0, stream>>>(
        itok, ptok, ipos, ppos, it_bf, pt_bf, ip_bf, pp_bf);

    transpose_w<<<dim3(EMBED / 32, EMBED / 32), blk, 0, stream>>>(Wip, wip_t, EMBED, EMBED);
    transpose_w<<<dim3(EMBED / 32, EMBED / 32), blk, 0, stream>>>(Wpp, wpp_t, EMBED, EMBED);
    transpose_w<<<dim3(EMBED / 32, EMBED / 32), blk, 0, stream>>>(Wq,  wq_t,  EMBED, EMBED);
    transpose_w<<<dim3(EMBED / 32, EMBED / 32), blk, 0, stream>>>(Wk,  wk_t,  EMBED, EMBED);
    transpose_w<<<dim3(EMBED / 32, EMBED / 32), blk, 0, stream>>>(Wv,  wv_t,  EMBED, EMBED);
    transpose_w<<<dim3(EMBED / 32, EMBED / 32), blk, 0, stream>>>(Wo,  wo_t,  EMBED, EMBED);
    transpose_w<<<dim3(FFDIM / 32, EMBED / 32), blk, 0, stream>>>(Wf1, wf1_t, EMBED, FFDIM);
    transpose_w<<<dim3(EMBED / 32, FFDIM / 32), blk, 0, stream>>>(Wf2, wf2_t, FFDIM, EMBED);

    const dim3 g768(EMBED / 128, MROWS / 128);   // 6 x 64
    const dim3 g1536(FFDIM / 128, MROWS / 128);  // 12 x 64

    // qin = image_tokens + image_pos@Wip + bip
    gemm_bt<0,0,1,1,0><<<g768, blk, 0, stream>>>(ip_bf, wip_t, bip, itok, qin_bf, nullptr, MROWS, EMBED, EMBED);
    // kin = point_tokens + point_pos@Wpp + bpp
    gemm_bt<0,0,1,1,0><<<g768, blk, 0, stream>>>(pp_bf, wpp_t, bpp, ptok, kin_bf, nullptr, MROWS, EMBED, EMBED);
    // qn = l2norm_heads(qin@Wq + bq)
    gemm_bt<1,0,0,1,0><<<g768, blk, 0, stream>>>(qin_bf, wq_t, bq, nullptr, qn_bf, nullptr, MROWS, EMBED, EMBED);
    // kn = l2norm_heads(kin@Wk + bk)
    gemm_bt<1,0,0,1,0><<<g768, blk, 0, stream>>>(kin_bf, wk_t, bk, nullptr, kn_bf, nullptr, MROWS, EMBED, EMBED);
    // v = point_tokens@Wv + bv
    gemm_bt<0,0,0,1,0><<<g768, blk, 0, stream>>>(pt_bf, wv_t, bv, nullptr, v_bf, nullptr, MROWS, EMBED, EMBED);

    transpose_v<<<dim3(SEQ / 64, BATCH * HEADS), blk, 0, stream>>>(v_bf, vt_bf);
    attn_kernel<<<dim3(SEQ / 64, BATCH * HEADS), blk, 0, stream>>>(qn_bf, kn_bf, vt_bf, attn_bf);

    // x1 = image_tokens + attn@Wo + bo
    gemm_bt<0,0,1,0,1><<<g768, blk, 0, stream>>>(attn_bf, wo_t, bo, itok, nullptr, x_f32, MROWS, EMBED, EMBED);
    layernorm_768<1><<<dim3(MROWS), blk, 0, stream>>>(x_f32, g1, b1, fused_f32, fused_bf);
    // h = gelu(fused@Wf1 + bf1)
    gemm_bt<0,1,0,1,0><<<g1536, blk, 0, stream>>>(fused_bf, wf1_t, bf1, nullptr, h_bf, nullptr, MROWS, FFDIM, EMBED);
    // x2 = fused + h@Wf2 + bf2
    gemm_bt<0,0,1,0,1><<<g768, blk, 0, stream>>>(h_bf, wf2_t, bf2, fused_f32, nullptr, x_f32, MROWS, EMBED, FFDIM);
    layernorm_768<0><<<dim3(MROWS), blk, 0, stream>>>(x_f32, g2, b2, out, nullptr);
}

// Round 2
// 561.289 us; speedup vs baseline: 1.1411x; 1.1411x over previous
//
#include <hip/hip_runtime.h>

#define EMBED 768
#define FFDIM 1536
#define BATCH 4
#define SEQ   2048
#define HEADS 12
#define MROWS (BATCH*SEQ)   // 8192

typedef __attribute__((ext_vector_type(4))) float  f32x4;
typedef __attribute__((ext_vector_type(8))) __bf16 bf16x8;
typedef __attribute__((ext_vector_type(4))) short  s16x4;

__device__ __forceinline__ short f2bf(float f) {
    union { float f; unsigned u; } x; x.f = f;
    unsigned r = x.u + 0x7fffu + ((x.u >> 16) & 1u);
    return (short)(r >> 16);
}

__device__ __forceinline__ void gll16(const void* g, void* l) {
    __builtin_amdgcn_global_load_lds(
        (const __attribute__((address_space(1))) void*)g,
        (__attribute__((address_space(3))) void*)l, 16, 0, 0);
}

// swizzled read of one 16B chunk from a 64-col (128B) row-major bf16 LDS tile
__device__ __forceinline__ bf16x8 ldsw(const short* base, int row, int chunk) {
    return *(const bf16x8*)((const char*)base + row * 128 + (((chunk ^ (row & 7))) << 4));
}

// ---------------- fp32 -> bf16 convert (4 tensors, same size) ----------------
__global__ __launch_bounds__(256) void cvt4_kernel(
    const float* __restrict__ s0, const float* __restrict__ s1,
    const float* __restrict__ s2, const float* __restrict__ s3,
    short* __restrict__ o0, short* __restrict__ o1,
    short* __restrict__ o2, short* __restrict__ o3)
{
    const float* s; short* o;
    switch (blockIdx.y) {
        case 0:  s = s0; o = o0; break;
        case 1:  s = s1; o = o1; break;
        case 2:  s = s2; o = o2; break;
        default: s = s3; o = o3; break;
    }
    size_t i = ((size_t)blockIdx.x * 256 + threadIdx.x) * 4;
    float4 v = *(const float4*)(s + i);
    s16x4 r;
    r[0] = f2bf(v.x); r[1] = f2bf(v.y); r[2] = f2bf(v.z); r[3] = f2bf(v.w);
    *(s16x4*)(o + i) = r;
}

// ---------------- weight transpose+convert: W[K][N] f32 -> Wt[N][K] bf16 ----------------
__global__ __launch_bounds__(256) void transpose_w(
    const float* __restrict__ W, short* __restrict__ Wt, int K, int N)
{
    __shared__ float tile[32][33];
    const int k0 = blockIdx.y * 32, n0 = blockIdx.x * 32;
    const int tx = threadIdx.x & 31, ty = threadIdx.x >> 5;  // 32 x 8
    #pragma unroll
    for (int i = 0; i < 32; i += 8)
        tile[ty + i][tx] = W[(size_t)(k0 + ty + i) * N + n0 + tx];
    __syncthreads();
    #pragma unroll
    for (int i = 0; i < 32; i += 8)
        Wt[(size_t)(n0 + ty + i) * K + k0 + tx] = f2bf(tile[tx][ty + i]);
}

// ---------------- v [B*SEQ][768] bf16 -> vt [B][H][64][SEQ] bf16 ----------------
__global__ __launch_bounds__(256) void transpose_v(
    const short* __restrict__ v, short* __restrict__ vt)
{
    __shared__ short tile[64][65];
    const int bh = blockIdx.y;
    const int b = bh / HEADS, h = bh % HEADS;
    const int k0 = blockIdx.x * 64;
    const int tx = threadIdx.x & 63, ty = threadIdx.x >> 6;  // 64 x 4
    #pragma unroll
    for (int i = 0; i < 64; i += 4)
        tile[ty + i][tx] = v[(size_t)(b * SEQ + k0 + ty + i) * EMBED + h * 64 + tx];
    __syncthreads();
    #pragma unroll
    for (int i = 0; i < 64; i += 4)
        vt[(size_t)(bh * 64 + ty + i) * SEQ + k0 + tx] = tile[tx][ty + i];
}

// ---------------- GEMM: out = act(A[M][K] @ Wt[N][K]^T + bias (+resid)) ----------------
// 128x128 tile, BK=32, 4 waves (2x2), double-buffered LDS, 1 barrier / K-step.
template<int L2N, int GELU_, int RES, int SBF, int SF32>
__global__ __launch_bounds__(256) void gemm_bt(
    const short* __restrict__ A, const short* __restrict__ Wt,
    const float* __restrict__ bias, const float* __restrict__ resid,
    short* __restrict__ outb, float* __restrict__ outf,
    int M, int N, int K)
{
    __shared__ short As[2][128][32];
    __shared__ short Bs[2][128][32];
    const int tid = threadIdx.x;
    const int mbase = blockIdx.y * 128, nbase = blockIdx.x * 128;
    const int wid = tid >> 6, lane = tid & 63;
    const int wm = wid >> 1, wn = wid & 1;
    const int l15 = lane & 15, lhi = lane >> 4;
    const int sr = tid >> 2;         // 0..63
    const int sc = (tid & 3) * 8;    // 0/8/16/24

    f32x4 acc[4][4] = {};

    const short* Ab = A  + (size_t)mbase * K;
    const short* Bb = Wt + (size_t)nbase * K;

#define GSTAGE(buf, kk)                                                         \
    gll16(Ab + (size_t)sr * K        + (kk) + sc, &As[buf][sr][sc]);            \
    gll16(Ab + (size_t)(64 + sr) * K + (kk) + sc, &As[buf][64 + sr][sc]);       \
    gll16(Bb + (size_t)sr * K        + (kk) + sc, &Bs[buf][sr][sc]);            \
    gll16(Bb + (size_t)(64 + sr) * K + (kk) + sc, &Bs[buf][64 + sr][sc]);

    GSTAGE(0, 0);
    __syncthreads();

    const int nk = K >> 5;
    for (int t = 0; t < nk; ++t) {
        const int cur = t & 1;
        if (t + 1 < nk) { GSTAGE(cur ^ 1, (t + 1) << 5); }
        bf16x8 av[4], bv[4];
        #pragma unroll
        for (int tt = 0; tt < 4; ++tt) {
            av[tt] = *(const bf16x8*)(&As[cur][wm * 64 + tt * 16 + l15][lhi * 8]);
            bv[tt] = *(const bf16x8*)(&Bs[cur][wn * 64 + tt * 16 + l15][lhi * 8]);
        }
        #pragma unroll
        for (int mt = 0; mt < 4; ++mt)
            #pragma unroll
            for (int nt = 0; nt < 4; ++nt)
                acc[mt][nt] = __builtin_amdgcn_mfma_f32_16x16x32_bf16(
                    av[mt], bv[nt], acc[mt][nt], 0, 0, 0);
        __syncthreads();
    }
#undef GSTAGE

    #pragma unroll
    for (int mt = 0; mt < 4; ++mt) {
        float vals[4][4];
        #pragma unroll
        for (int nt = 0; nt < 4; ++nt) {
            const int col = nbase + wn * 64 + nt * 16 + l15;
            const float bc = bias[col];
            #pragma unroll
            for (int j = 0; j < 4; ++j) vals[nt][j] = acc[mt][nt][j] + bc;
        }
        if (RES) {
            #pragma unroll
            for (int nt = 0; nt < 4; ++nt) {
                const int col = nbase + wn * 64 + nt * 16 + l15;
                #pragma unroll
                for (int j = 0; j < 4; ++j) {
                    const int row = mbase + wm * 64 + mt * 16 + lhi * 4 + j;
                    vals[nt][j] += resid[(size_t)row * N + col];
                }
            }
        }
        if (L2N) {  // l2-normalize over this wave's 64-col head span
            #pragma unroll
            for (int j = 0; j < 4; ++j) {
                float s = 0.f;
                #pragma unroll
                for (int nt = 0; nt < 4; ++nt) s += vals[nt][j] * vals[nt][j];
                s += __shfl_xor(s, 1); s += __shfl_xor(s, 2);
                s += __shfl_xor(s, 4); s += __shfl_xor(s, 8);
                const float inv = 1.0f / fmaxf(sqrtf(s), 1e-12f);
                #pragma unroll
                for (int nt = 0; nt < 4; ++nt) vals[nt][j] *= inv;
            }
        }
        if (GELU_) {
            #pragma unroll
            for (int nt = 0; nt < 4; ++nt)
                #pragma unroll
                for (int j = 0; j < 4; ++j) {
                    const float v = vals[nt][j];
                    vals[nt][j] = 0.5f * v * (1.0f + erff(v * 0.70710678118654752f));
                }
        }
        #pragma unroll
        for (int nt = 0; nt < 4; ++nt) {
            const int col = nbase + wn * 64 + nt * 16 + l15;
            #pragma unroll
            for (int j = 0; j < 4; ++j) {
                const int row = mbase + wm * 64 + mt * 16 + lhi * 4 + j;
                if (SBF)  outb[(size_t)row * N + col] = f2bf(vals[nt][j]);
                if (SF32) outf[(size_t)row * N + col] = vals[nt][j];
            }
        }
    }
}

// ---------------- attention: one-pass exp-sum (scores in [-1,1]) ----------------
// QBLK=128, 8 waves (512 thr); K/V double-buffered; XOR-swizzled LDS; 1 barrier/tile.
__global__ __launch_bounds__(512) void attn_kernel(
    const short* __restrict__ qn, const short* __restrict__ kn,
    const short* __restrict__ vt, short* __restrict__ outp)
{
    __shared__ short Qs[128][64];      // 16 KB, swizzled
    __shared__ short Ks[2][64][64];    // 16 KB, swizzled
    __shared__ short Vs[2][64][64];    // 16 KB, swizzled; [d][k]
    __shared__ short Ps[128][64];      // 16 KB, swizzled; wave-private 16-row slices

    const int bh = blockIdx.y;
    const int b = bh / HEADS, h = bh % HEADS;
    const int q0 = blockIdx.x * 128;
    const int tid = threadIdx.x, wid = tid >> 6, lane = tid & 63;
    const int l15 = lane & 15, lhi = lane >> 4;
    const int srow = tid >> 3;        // 0..63
    const int schk = tid & 7;         // 0..7

    // ---- stage Q (swizzled source; linear LDS dest) ----
    #pragma unroll
    for (int p = 0; p < 2; ++p) {
        const int cid = p * 512 + tid;
        const int r = cid >> 3, c = cid & 7;
        gll16(qn + (size_t)(b * SEQ + q0 + r) * EMBED + h * 64 + ((c ^ (r & 7)) * 8),
              &Qs[r][c * 8]);
    }
    // ---- stage K,V tile 0 into buf 0 ----
    gll16(kn + (size_t)(b * SEQ + srow) * EMBED + h * 64 + ((schk ^ (srow & 7)) * 8),
          &Ks[0][srow][schk * 8]);
    gll16(vt + (size_t)(bh * 64 + srow) * SEQ + ((schk ^ (srow & 7)) * 8),
          &Vs[0][srow][schk * 8]);
    __syncthreads();

    const bf16x8 aq0 = ldsw(&Qs[0][0], wid * 16 + l15, lhi);
    const bf16x8 aq1 = ldsw(&Qs[0][0], wid * 16 + l15, 4 + lhi);

    f32x4 acc_o[4] = {};
    float rowsum[4] = {0.f, 0.f, 0.f, 0.f};
    char* const ps_base = (char*)&Ps[0][0];

    for (int kt = 0; kt < SEQ / 64; ++kt) {
        const int cur = kt & 1;
        if (kt + 1 < SEQ / 64) {
            const int k0n = (kt + 1) * 64;
            gll16(kn + (size_t)(b * SEQ + k0n + srow) * EMBED + h * 64 + ((schk ^ (srow & 7)) * 8),
                  &Ks[cur ^ 1][srow][schk * 8]);
            gll16(vt + (size_t)(bh * 64 + srow) * SEQ + k0n + ((schk ^ (srow & 7)) * 8),
                  &Vs[cur ^ 1][srow][schk * 8]);
        }

        // S = Q K^T -> P = exp(S) into wave-private Ps rows
        #pragma unroll
        for (int nt = 0; nt < 4; ++nt) {
            bf16x8 bk0 = ldsw(&Ks[cur][0][0], nt * 16 + l15, lhi);
            bf16x8 bk1 = ldsw(&Ks[cur][0][0], nt * 16 + l15, 4 + lhi);
            f32x4 s = {0.f, 0.f, 0.f, 0.f};
            s = __builtin_amdgcn_mfma_f32_16x16x32_bf16(aq0, bk0, s, 0, 0, 0);
            s = __builtin_amdgcn_mfma_f32_16x16x32_bf16(aq1, bk1, s, 0, 0, 0);
            #pragma unroll
            for (int j = 0; j < 4; ++j) {
                const float e = __expf(s[j]);
                rowsum[j] += e;
                const int q = wid * 16 + lhi * 4 + j;
                const int k = nt * 16 + l15;
                const int chunk = k >> 3;
                *(short*)(ps_base + q * 128 + ((chunk ^ (q & 7)) << 4) + (k & 7) * 2) = f2bf(e);
            }
        }

        // O += P V   (no barrier: Ps slices are wave-private)
        #pragma unroll
        for (int ks = 0; ks < 2; ++ks) {
            bf16x8 ap = ldsw(&Ps[0][0], wid * 16 + l15, ks * 4 + lhi);
            #pragma unroll
            for (int dt = 0; dt < 4; ++dt) {
                bf16x8 bvv = ldsw(&Vs[cur][0][0], dt * 16 + l15, ks * 4 + lhi);
                acc_o[dt] = __builtin_amdgcn_mfma_f32_16x16x32_bf16(ap, bvv, acc_o[dt], 0, 0, 0);
            }
        }
        __syncthreads();  // drains vmcnt (next K/V staged) + syncs buffer swap
    }

    #pragma unroll
    for (int j = 0; j < 4; ++j) {
        float s = rowsum[j];
        s += __shfl_xor(s, 1); s += __shfl_xor(s, 2);
        s += __shfl_xor(s, 4); s += __shfl_xor(s, 8);
        rowsum[j] = s;
    }

    #pragma unroll
    for (int dt = 0; dt < 4; ++dt)
        #pragma unroll
        for (int j = 0; j < 4; ++j) {
            const int row = q0 + wid * 16 + lhi * 4 + j;
            const int col = h * 64 + dt * 16 + l15;
            outp[(size_t)(b * SEQ + row) * EMBED + col] = f2bf(acc_o[dt][j] / rowsum[j]);
        }
}

// ---------------- layernorm over 768 cols ----------------
template<int SBF>
__global__ __launch_bounds__(256) void layernorm_768(
    const float* __restrict__ x, const float* __restrict__ g, const float* __restrict__ bb,
    float* __restrict__ outf, short* __restrict__ outb)
{
    const int row = blockIdx.x;
    const float* xr = x + (size_t)row * EMBED;
    const int t = threadIdx.x;
    const float v0 = xr[t], v1 = xr[t + 256], v2 = xr[t + 512];
    float s = v0 + v1 + v2;
    #pragma unroll
    for (int m = 1; m < 64; m <<= 1) s += __shfl_xor(s, m);
    __shared__ float red[4];
    __shared__ float red2[4];
    const int wid = t >> 6, lane = t & 63;
    if (lane == 0) red[wid] = s;
    __syncthreads();
    const float mu = (red[0] + red[1] + red[2] + red[3]) * (1.0f / 768.0f);
    const float d0 = v0 - mu, d1 = v1 - mu, d2 = v2 - mu;
    float ss = d0 * d0 + d1 * d1 + d2 * d2;
    #pragma unroll
    for (int m = 1; m < 64; m <<= 1) ss += __shfl_xor(ss, m);
    if (lane == 0) red2[wid] = ss;
    __syncthreads();
    const float var = (red2[0] + red2[1] + red2[2] + red2[3]) * (1.0f / 768.0f);
    const float inv = rsqrtf(var + 1e-5f);
    const float y0 = d0 * inv * g[t] + bb[t];
    const float y1 = d1 * inv * g[t + 256] + bb[t + 256];
    const float y2 = d2 * inv * g[t + 512] + bb[t + 512];
    float* of = outf + (size_t)row * EMBED;
    of[t] = y0; of[t + 256] = y1; of[t + 512] = y2;
    if (SBF) {
        short* ob = outb + (size_t)row * EMBED;
        ob[t] = f2bf(y0); ob[t + 256] = f2bf(y1); ob[t + 512] = f2bf(y2);
    }
}

extern "C" void kernel_launch(void* const* d_in, const int* in_sizes, int n_in,
                              void* d_out, int out_size, void* d_ws, size_t ws_size,
                              hipStream_t stream)
{
    (void)in_sizes; (void)n_in; (void)out_size; (void)ws_size;
    const float* itok = (const float*)d_in[0];
    const float* ptok = (const float*)d_in[1];
    const float* ipos = (const float*)d_in[2];
    const float* ppos = (const float*)d_in[3];
    const float* Wip = (const float*)d_in[4];  const float* bip = (const float*)d_in[5];
    const float* Wpp = (const float*)d_in[6];  const float* bpp = (const float*)d_in[7];
    const float* Wq  = (const float*)d_in[8];  const float* bq  = (const float*)d_in[9];
    const float* Wk  = (const float*)d_in[10]; const float* bk  = (const float*)d_in[11];
    const float* Wv  = (const float*)d_in[12]; const float* bv  = (const float*)d_in[13];
    const float* Wo  = (const float*)d_in[14]; const float* bo  = (const float*)d_in[15];
    const float* g1  = (const float*)d_in[16]; const float* b1  = (const float*)d_in[17];
    const float* g2  = (const float*)d_in[18]; const float* b2  = (const float*)d_in[19];
    const float* Wf1 = (const float*)d_in[20]; const float* bf1 = (const float*)d_in[21];
    const float* Wf2 = (const float*)d_in[22]; const float* bf2 = (const float*)d_in[23];
    float* out = (float*)d_out;

    char* ws = (char*)d_ws;
    constexpr size_t SZ_BF  = (size_t)MROWS * EMBED * 2;   // 12.58 MB
    constexpr size_t SZ_F32 = (size_t)MROWS * EMBED * 4;   // 25.17 MB
    constexpr size_t W768B  = (size_t)EMBED * EMBED * 2;
    constexpr size_t W1536B = (size_t)EMBED * FFDIM * 2;

    size_t o = 0;
    short* it_bf    = (short*)(ws + o); o += SZ_BF;
    short* pt_bf    = (short*)(ws + o); o += SZ_BF;
    short* ip_bf    = (short*)(ws + o); o += SZ_BF;   // reused as v_bf after G1
    short* pp_bf    = (short*)(ws + o); o += SZ_BF;   // reused as vt_bf after G2
    short* qin_bf   = (short*)(ws + o); o += SZ_BF;   // qin+kin reused as h_bf
    short* kin_bf   = (short*)(ws + o); o += SZ_BF;
    short* qn_bf    = (short*)(ws + o); o += SZ_BF;
    short* kn_bf    = (short*)(ws + o); o += SZ_BF;
    short* attn_bf  = (short*)(ws + o); o += SZ_BF;
    float* x_f32    = (float*)(ws + o); o += SZ_F32;  // x1 then x2
    short* fused_bf = (short*)(ws + o); o += SZ_BF;
    float* fused_f32= (float*)(ws + o); o += SZ_F32;
    short* wip_t = (short*)(ws + o); o += W768B;
    short* wpp_t = (short*)(ws + o); o += W768B;
    short* wq_t  = (short*)(ws + o); o += W768B;
    short* wk_t  = (short*)(ws + o); o += W768B;
    short* wv_t  = (short*)(ws + o); o += W768B;
    short* wo_t  = (short*)(ws + o); o += W768B;
    short* wf1_t = (short*)(ws + o); o += W1536B;
    short* wf2_t = (short*)(ws + o); o += W1536B;
    short* v_bf  = ip_bf;
    short* vt_bf = pp_bf;
    short* h_bf  = qin_bf;  // spans qin+kin (25.17 MB)

    const dim3 blk(256);

    cvt4_kernel<<<dim3(MROWS * EMBED / 1024, 4), blk, 0, stream>>>(
        itok, ptok, ipos, ppos, it_bf, pt_bf, ip_bf, pp_bf);

    transpose_w<<<dim3(EMBED / 32, EMBED / 32), blk, 0, stream>>>(Wip, wip_t, EMBED, EMBED);
    transpose_w<<<dim3(EMBED / 32, EMBED / 32), blk, 0, stream>>>(Wpp, wpp_t, EMBED, EMBED);
    transpose_w<<<dim3(EMBED / 32, EMBED / 32), blk, 0, stream>>>(Wq,  wq_t,  EMBED, EMBED);
    transpose_w<<<dim3(EMBED / 32, EMBED / 32), blk, 0, stream>>>(Wk,  wk_t,  EMBED, EMBED);
    transpose_w<<<dim3(EMBED / 32, EMBED / 32), blk, 0, stream>>>(Wv,  wv_t,  EMBED, EMBED);
    transpose_w<<<dim3(EMBED / 32, EMBED / 32), blk, 0, stream>>>(Wo,  wo_t,  EMBED, EMBED);
    transpose_w<<<dim3(FFDIM / 32, EMBED / 32), blk, 0, stream>>>(Wf1, wf1_t, EMBED, FFDIM);
    transpose_w<<<dim3(EMBED / 32, FFDIM / 32), blk, 0, stream>>>(Wf2, wf2_t, FFDIM, EMBED);

    const dim3 g768(EMBED / 128, MROWS / 128);   // 6 x 64
    const dim3 g1536(FFDIM / 128, MROWS / 128);  // 12 x 64

    // qin = image_tokens + image_pos@Wip + bip
    gemm_bt<0,0,1,1,0><<<g768, blk, 0, stream>>>(ip_bf, wip_t, bip, itok, qin_bf, nullptr, MROWS, EMBED, EMBED);
    // kin = point_tokens + point_pos@Wpp + bpp
    gemm_bt<0,0,1,1,0><<<g768, blk, 0, stream>>>(pp_bf, wpp_t, bpp, ptok, kin_bf, nullptr, MROWS, EMBED, EMBED);
    // qn = l2norm_heads(qin@Wq + bq)
    gemm_bt<1,0,0,1,0><<<g768, blk, 0, stream>>>(qin_bf, wq_t, bq, nullptr, qn_bf, nullptr, MROWS, EMBED, EMBED);
    // kn = l2norm_heads(kin@Wk + bk)
    gemm_bt<1,0,0,1,0><<<g768, blk, 0, stream>>>(kin_bf, wk_t, bk, nullptr, kn_bf, nullptr, MROWS, EMBED, EMBED);
    // v = point_tokens@Wv + bv
    gemm_bt<0,0,0,1,0><<<g768, blk, 0, stream>>>(pt_bf, wv_t, bv, nullptr, v_bf, nullptr, MROWS, EMBED, EMBED);

    transpose_v<<<dim3(SEQ / 64, BATCH * HEADS), blk, 0, stream>>>(v_bf, vt_bf);
    attn_kernel<<<dim3(SEQ / 128, BATCH * HEADS), dim3(512), 0, stream>>>(qn_bf, kn_bf, vt_bf, attn_bf);

    // x1 = image_tokens + attn@Wo + bo
    gemm_bt<0,0,1,0,1><<<g768, blk, 0, stream>>>(attn_bf, wo_t, bo, itok, nullptr, x_f32, MROWS, EMBED, EMBED);
    layernorm_768<1><<<dim3(MROWS), blk, 0, stream>>>(x_f32, g1, b1, fused_f32, fused_bf);
    // h = gelu(fused@Wf1 + bf1)
    gemm_bt<0,1,0,1,0><<<g1536, blk, 0, stream>>>(fused_bf, wf1_t, bf1, nullptr, h_bf, nullptr, MROWS, FFDIM, EMBED);
    // x2 = fused + h@Wf2 + bf2
    gemm_bt<0,0,1,0,1><<<g768, blk, 0, stream>>>(h_bf, wf2_t, bf2, fused_f32, nullptr, x_f32, MROWS, EMBED, FFDIM);
    layernorm_768<0><<<dim3(MROWS), blk, 0, stream>>>(x_f32, g2, b2, out, nullptr);
}

// Round 3
// 519.431 us; speedup vs baseline: 1.2330x; 1.0806x over previous
//
#include <hip/hip_runtime.h>

#define EMBED 768
#define FFDIM 1536
#define BATCH 4
#define SEQ   2048
#define HEADS 12
#define MROWS (BATCH*SEQ)   // 8192

typedef __attribute__((ext_vector_type(4)))  float  f32x4;
typedef __attribute__((ext_vector_type(16))) float  f32x16;
typedef __attribute__((ext_vector_type(8)))  __bf16 bf16x8;
typedef __attribute__((ext_vector_type(4)))  short  s16x4;

__device__ __forceinline__ short f2bf(float f) {
    union { float f; unsigned u; } x; x.f = f;
    unsigned r = x.u + 0x7fffu + ((x.u >> 16) & 1u);
    return (short)(r >> 16);
}

__device__ __forceinline__ unsigned cvtpk(float lo, float hi) {
    unsigned r;
    asm("v_cvt_pk_bf16_f32 %0, %1, %2" : "=v"(r) : "v"(lo), "v"(hi));
    return r;
}

__device__ __forceinline__ void gll16(const void* g, void* l) {
    __builtin_amdgcn_global_load_lds(
        (const __attribute__((address_space(1))) void*)g,
        (__attribute__((address_space(3))) void*)l, 16, 0, 0);
}

// swizzled read of one 16B chunk from a 64-col (128B-stride) row-major bf16 LDS tile
__device__ __forceinline__ bf16x8 ldsw(const short* base, int row, int chunk) {
    return *(const bf16x8*)((const char*)base + row * 128 + (((chunk ^ (row & 7))) << 4));
}

// ---------------- fp32 -> bf16 convert (3 tensors, same size) ----------------
__global__ __launch_bounds__(256) void cvt3_kernel(
    const float* __restrict__ s0, const float* __restrict__ s1,
    const float* __restrict__ s2,
    short* __restrict__ o0, short* __restrict__ o1, short* __restrict__ o2)
{
    const float* s; short* o;
    switch (blockIdx.y) {
        case 0:  s = s0; o = o0; break;
        case 1:  s = s1; o = o1; break;
        default: s = s2; o = o2; break;
    }
    size_t i = ((size_t)blockIdx.x * 256 + threadIdx.x) * 4;
    float4 v = *(const float4*)(s + i);
    s16x4 r;
    r[0] = f2bf(v.x); r[1] = f2bf(v.y); r[2] = f2bf(v.z); r[3] = f2bf(v.w);
    *(s16x4*)(o + i) = r;
}

// ---------------- weight transpose+convert: W[K][N] f32 -> Wt[N][K] bf16 ----------------
__global__ __launch_bounds__(256) void transpose_w(
    const float* __restrict__ W, short* __restrict__ Wt, int K, int N)
{
    __shared__ float tile[32][33];
    const int k0 = blockIdx.y * 32, n0 = blockIdx.x * 32;
    const int tx = threadIdx.x & 31, ty = threadIdx.x >> 5;  // 32 x 8
    #pragma unroll
    for (int i = 0; i < 32; i += 8)
        tile[ty + i][tx] = W[(size_t)(k0 + ty + i) * N + n0 + tx];
    __syncthreads();
    #pragma unroll
    for (int i = 0; i < 32; i += 8)
        Wt[(size_t)(n0 + ty + i) * K + k0 + tx] = f2bf(tile[tx][ty + i]);
}

// ---------------- v [B*SEQ][768] bf16 -> vt [B][H][64][SEQ] bf16 ----------------
__global__ __launch_bounds__(256) void transpose_v(
    const short* __restrict__ v, short* __restrict__ vt)
{
    __shared__ short tile[64][65];
    const int bh = blockIdx.y;
    const int b = bh / HEADS, h = bh % HEADS;
    const int k0 = blockIdx.x * 64;
    const int tx = threadIdx.x & 63, ty = threadIdx.x >> 6;  // 64 x 4
    #pragma unroll
    for (int i = 0; i < 64; i += 4)
        tile[ty + i][tx] = v[(size_t)(b * SEQ + k0 + ty + i) * EMBED + h * 64 + tx];
    __syncthreads();
    #pragma unroll
    for (int i = 0; i < 64; i += 4)
        vt[(size_t)(bh * 64 + ty + i) * SEQ + k0 + tx] = tile[tx][ty + i];
}

// ---------------- GEMM core: out = act(A[M][K] @ Wt[N][K]^T + bias (+resid)) ----------------
// 128x128 tile, BK=32, 4 waves (2x2), double-buffered LDS, 1 barrier / K-step.
template<int L2N, int GELU_, int SBF, int SF32>
__device__ __forceinline__ void gemm_core(
    const short* __restrict__ A, const short* __restrict__ Wt,
    const float* __restrict__ bias, const float* __restrict__ resid,
    short* __restrict__ outb, float* __restrict__ outf, int N, int K)
{
    __shared__ short As[2][128][32];
    __shared__ short Bs[2][128][32];
    const int tid = threadIdx.x;
    const int mbase = blockIdx.y * 128, nbase = blockIdx.x * 128;
    const int wid = tid >> 6, lane = tid & 63;
    const int wm = wid >> 1, wn = wid & 1;
    const int l15 = lane & 15, lhi = lane >> 4;
    const int sr = tid >> 2;         // 0..63
    const int sc = (tid & 3) * 8;    // 0/8/16/24

    f32x4 acc[4][4] = {};

    const short* Ab = A  + (size_t)mbase * K;
    const short* Bb = Wt + (size_t)nbase * K;

#define GSTAGE(buf, kk)                                                         \
    gll16(Ab + (size_t)sr * K        + (kk) + sc, &As[buf][sr][sc]);            \
    gll16(Ab + (size_t)(64 + sr) * K + (kk) + sc, &As[buf][64 + sr][sc]);       \
    gll16(Bb + (size_t)sr * K        + (kk) + sc, &Bs[buf][sr][sc]);            \
    gll16(Bb + (size_t)(64 + sr) * K + (kk) + sc, &Bs[buf][64 + sr][sc]);

    GSTAGE(0, 0);
    __syncthreads();

    const int nk = K >> 5;
    for (int t = 0; t < nk; ++t) {
        const int cur = t & 1;
        if (t + 1 < nk) { GSTAGE(cur ^ 1, (t + 1) << 5); }
        bf16x8 av[4], bv[4];
        #pragma unroll
        for (int tt = 0; tt < 4; ++tt) {
            av[tt] = *(const bf16x8*)(&As[cur][wm * 64 + tt * 16 + l15][lhi * 8]);
            bv[tt] = *(const bf16x8*)(&Bs[cur][wn * 64 + tt * 16 + l15][lhi * 8]);
        }
        #pragma unroll
        for (int mt = 0; mt < 4; ++mt)
            #pragma unroll
            for (int nt = 0; nt < 4; ++nt)
                acc[mt][nt] = __builtin_amdgcn_mfma_f32_16x16x32_bf16(
                    av[mt], bv[nt], acc[mt][nt], 0, 0, 0);
        __syncthreads();
    }
#undef GSTAGE

    #pragma unroll
    for (int mt = 0; mt < 4; ++mt) {
        float vals[4][4];
        #pragma unroll
        for (int nt = 0; nt < 4; ++nt) {
            const int col = nbase + wn * 64 + nt * 16 + l15;
            const float bc = bias[col];
            #pragma unroll
            for (int j = 0; j < 4; ++j) vals[nt][j] = acc[mt][nt][j] + bc;
        }
        if (resid != nullptr) {
            #pragma unroll
            for (int nt = 0; nt < 4; ++nt) {
                const int col = nbase + wn * 64 + nt * 16 + l15;
                #pragma unroll
                for (int j = 0; j < 4; ++j) {
                    const int row = mbase + wm * 64 + mt * 16 + lhi * 4 + j;
                    vals[nt][j] += resid[(size_t)row * N + col];
                }
            }
        }
        if (L2N) {  // l2-normalize over this wave's 64-col head span
            #pragma unroll
            for (int j = 0; j < 4; ++j) {
                float s = 0.f;
                #pragma unroll
                for (int nt = 0; nt < 4; ++nt) s += vals[nt][j] * vals[nt][j];
                s += __shfl_xor(s, 1); s += __shfl_xor(s, 2);
                s += __shfl_xor(s, 4); s += __shfl_xor(s, 8);
                const float inv = 1.0f / fmaxf(sqrtf(s), 1e-12f);
                #pragma unroll
                for (int nt = 0; nt < 4; ++nt) vals[nt][j] *= inv;
            }
        }
        if (GELU_) {
            #pragma unroll
            for (int nt = 0; nt < 4; ++nt)
                #pragma unroll
                for (int j = 0; j < 4; ++j) {
                    const float v = vals[nt][j];
                    vals[nt][j] = 0.5f * v * (1.0f + erff(v * 0.70710678118654752f));
                }
        }
        #pragma unroll
        for (int nt = 0; nt < 4; ++nt) {
            const int col = nbase + wn * 64 + nt * 16 + l15;
            #pragma unroll
            for (int j = 0; j < 4; ++j) {
                const int row = mbase + wm * 64 + mt * 16 + lhi * 4 + j;
                if (SBF)  outb[(size_t)row * N + col] = f2bf(vals[nt][j]);
                if (SF32) outf[(size_t)row * N + col] = vals[nt][j];
            }
        }
    }
}

template<int L2N, int GELU_, int SBF, int SF32>
__global__ __launch_bounds__(256) void gemm_bt(
    const short* __restrict__ A, const short* __restrict__ Wt,
    const float* __restrict__ bias, const float* __restrict__ resid,
    short* __restrict__ outb, float* __restrict__ outf, int N, int K)
{
    gemm_core<L2N, GELU_, SBF, SF32>(A, Wt, bias, resid, outb, outf, N, K);
}

// three independent N=768 K=768 GEMMs in one dispatch (grid.z selects)
__global__ __launch_bounds__(256) void gemm3_kernel(
    const short* A0, const short* W0, const float* b0, const float* r0, short* o0,
    const short* A1, const short* W1, const float* b1, const float* r1, short* o1,
    const short* A2, const short* W2, const float* b2, const float* r2, short* o2)
{
    const short *A, *W; const float *bi, *re; short* ob;
    if (blockIdx.z == 0)      { A = A0; W = W0; bi = b0; re = r0; ob = o0; }
    else if (blockIdx.z == 1) { A = A1; W = W1; bi = b1; re = r1; ob = o1; }
    else                      { A = A2; W = W2; bi = b2; re = r2; ob = o2; }
    gemm_core<0, 0, 1, 0>(A, W, bi, re, ob, nullptr, EMBED, EMBED);
}

// two l2norm projection GEMMs (q,k) in one dispatch
__global__ __launch_bounds__(256) void gemm2_kernel(
    const short* A0, const short* W0, const float* b0, short* o0,
    const short* A1, const short* W1, const float* b1, short* o1)
{
    const short *A, *W; const float *bi; short* ob;
    if (blockIdx.z == 0) { A = A0; W = W0; bi = b0; ob = o0; }
    else                 { A = A1; W = W1; bi = b1; ob = o1; }
    gemm_core<1, 0, 1, 0>(A, W, bi, nullptr, ob, nullptr, EMBED, EMBED);
}

// ---------------- attention: 32x32x16 MFMA, in-register P (swapped QK^T) ----------------
// 4 waves x 32 q = 128 q/block; K/V double-buffered + swizzled; Q + P + O in registers.
__global__ __launch_bounds__(256) void attn_kernel(
    const short* __restrict__ qn, const short* __restrict__ kn,
    const short* __restrict__ vt, short* __restrict__ outp)
{
    __shared__ short Ks[2][64][64];    // 16 KB (reused as O-transpose buffer at end)
    __shared__ short Vs[2][64][64];    // 16 KB; Vs[d][k]

    const int bh = blockIdx.y;
    const int b = bh / HEADS, h = bh % HEADS;
    const int q0 = blockIdx.x * 128;
    const int tid = threadIdx.x, wq = tid >> 6, lane = tid & 63;
    const int l31 = lane & 31, hi = lane >> 5;
    const int srow = tid >> 3;        // 0..31 (staging row within half-tile)
    const int schk = tid & 7;         // 0..7  (staging chunk)

    // Q as B-fragments in registers: lane holds Q[q = q0+wq*32+l31][kk = t*16 + hi*8 + 0..7]
    const size_t qrow = (size_t)(b * SEQ + q0 + wq * 32 + l31) * EMBED + h * 64;
    bf16x8 qf[4];
    #pragma unroll
    for (int t = 0; t < 4; ++t)
        qf[t] = *(const bf16x8*)(qn + qrow + t * 16 + hi * 8);

    const short* kbase = kn + (size_t)b * SEQ * EMBED + h * 64;
    const short* vbase = vt + (size_t)bh * 64 * SEQ;

    // staging keeps global_load_lds contract: per wave-call dest = uniform base + lane*16
#define ASTAGE(buf, k0x) do {                                                            \
    _Pragma("unroll")                                                                    \
    for (int rr = 0; rr < 2; ++rr) {                                                     \
        const int row = rr * 32 + srow;                                                  \
        gll16(kbase + (size_t)((k0x) + row) * EMBED + ((schk ^ (row & 7)) * 8),          \
              &Ks[buf][row][schk * 8]);                                                  \
        gll16(vbase + (size_t)row * SEQ + (k0x) + ((schk ^ (row & 7)) * 8),              \
              &Vs[buf][row][schk * 8]);                                                  \
    }                                                                                    \
} while (0)

    ASTAGE(0, 0);
    __syncthreads();

    f32x16 acc_o[2] = {};
    float rsum = 0.f;
    const int NT = SEQ / 64;

    for (int kt = 0; kt < NT; ++kt) {
        const int cur = kt & 1;
        if (kt + 1 < NT) { ASTAGE(cur ^ 1, (kt + 1) * 64); }

        // S^T = mfma(K, Q): lane holds S^T[k][q=l31]; k = kb*32 + (reg&3)+8*(reg>>2)+4*hi
        f32x16 s0 = {}, s1 = {};
        #pragma unroll
        for (int t = 0; t < 4; ++t) {
            bf16x8 kf0 = ldsw(&Ks[cur][0][0], l31,      t * 2 + hi);
            bf16x8 kf1 = ldsw(&Ks[cur][0][0], 32 + l31, t * 2 + hi);
            s0 = __builtin_amdgcn_mfma_f32_32x32x16_bf16(kf0, qf[t], s0, 0, 0, 0);
            s1 = __builtin_amdgcn_mfma_f32_32x32x16_bf16(kf1, qf[t], s1, 0, 0, 0);
        }

        // P = exp(S) (scores bounded in [-1,1]; no max-tracking needed)
        float e0[16], e1[16];
        #pragma unroll
        for (int i = 0; i < 16; ++i) { const float e = __expf(s0[i]); rsum += e; e0[i] = e; }
        #pragma unroll
        for (int i = 0; i < 16; ++i) { const float e = __expf(s1[i]); rsum += e; e1[i] = e; }

        // pack to bf16 words: w[kb][2a+m] covers k-pair kb*32 + 8a + 4*hi + 2m
        unsigned w[2][8], sw[2][8];
        #pragma unroll
        for (int a = 0; a < 4; ++a) {
            w[0][2*a]   = cvtpk(e0[4*a],   e0[4*a+1]);
            w[0][2*a+1] = cvtpk(e0[4*a+2], e0[4*a+3]);
            w[1][2*a]   = cvtpk(e1[4*a],   e1[4*a+1]);
            w[1][2*a+1] = cvtpk(e1[4*a+2], e1[4*a+3]);
        }
        #pragma unroll
        for (int kb = 0; kb < 2; ++kb)
            #pragma unroll
            for (int i = 0; i < 8; ++i)
                sw[kb][i] = (unsigned)__shfl_xor((int)w[kb][i], 32);

        // O^T += mfma(V^T, P^T): B-frag needs k-octet 16*ks + 8*hi + 0..7
        #pragma unroll
        for (int kb = 0; kb < 2; ++kb) {
            #pragma unroll
            for (int ks = 0; ks < 2; ++ks) {
                union { unsigned u[4]; bf16x8 v; } pf;
                pf.u[0] = hi ? sw[kb][4*ks+2] : w[kb][4*ks];
                pf.u[1] = hi ? sw[kb][4*ks+3] : w[kb][4*ks+1];
                pf.u[2] = hi ? w[kb][4*ks+2]  : sw[kb][4*ks];
                pf.u[3] = hi ? w[kb][4*ks+3]  : sw[kb][4*ks+1];
                #pragma unroll
                for (int db = 0; db < 2; ++db) {
                    bf16x8 vf = ldsw(&Vs[cur][0][0], db * 32 + l31, kb * 4 + ks * 2 + hi);
                    acc_o[db] = __builtin_amdgcn_mfma_f32_32x32x16_bf16(vf, pf.v, acc_o[db], 0, 0, 0);
                }
            }
        }
        __syncthreads();  // drains vmcnt (prefetch) + protects buffer swap
    }
#undef ASTAGE

    // finish softmax denominator (k-halves split across lane pairs l, l^32)
    const float rtot = rsum + __shfl_xor(rsum, 32);
    const float rinv = 1.0f / rtot;

    // O^T -> LDS (swizzled) -> coalesced global store. Reuse Ks region (16 KB = 128 q x 64 d).
    short* Osb = &Ks[0][0][0];
    const int ql = wq * 32 + l31;
    #pragma unroll
    for (int db = 0; db < 2; ++db)
        #pragma unroll
        for (int a = 0; a < 4; ++a) {
            // d = db*32 + 8a + 4*hi + {0..3}
            const float v0 = acc_o[db][4*a]   * rinv, v1 = acc_o[db][4*a+1] * rinv;
            const float v2 = acc_o[db][4*a+2] * rinv, v3 = acc_o[db][4*a+3] * rinv;
            uint2 pw; pw.x = cvtpk(v0, v1); pw.y = cvtpk(v2, v3);
            const int byteoff = ql * 128 + (((db * 4 + a) ^ (ql & 7)) << 4) + hi * 8;
            *(uint2*)((char*)Osb + byteoff) = pw;
        }
    __syncthreads();
    #pragma unroll
    for (int p = 0; p < 2; ++p) {
        const int r = p * 64 + (tid >> 2);
        #pragma unroll
        for (int i = 0; i < 2; ++i) {
            const int c = (tid & 3) * 2 + i;
            bf16x8 v = ldsw(Osb, r, c);
            *(bf16x8*)(outp + (size_t)(b * SEQ + q0 + r) * EMBED + h * 64 + c * 8) = v;
        }
    }
}

// ---------------- layernorm over 768 cols ----------------
template<int SBF>
__global__ __launch_bounds__(256) void layernorm_768(
    const float* __restrict__ x, const float* __restrict__ g, const float* __restrict__ bb,
    float* __restrict__ outf, short* __restrict__ outb)
{
    const int row = blockIdx.x;
    const float* xr = x + (size_t)row * EMBED;
    const int t = threadIdx.x;
    const float v0 = xr[t], v1 = xr[t + 256], v2 = xr[t + 512];
    float s = v0 + v1 + v2;
    #pragma unroll
    for (int m = 1; m < 64; m <<= 1) s += __shfl_xor(s, m);
    __shared__ float red[4];
    __shared__ float red2[4];
    const int wid = t >> 6, lane = t & 63;
    if (lane == 0) red[wid] = s;
    __syncthreads();
    const float mu = (red[0] + red[1] + red[2] + red[3]) * (1.0f / 768.0f);
    const float d0 = v0 - mu, d1 = v1 - mu, d2 = v2 - mu;
    float ss = d0 * d0 + d1 * d1 + d2 * d2;
    #pragma unroll
    for (int m = 1; m < 64; m <<= 1) ss += __shfl_xor(ss, m);
    if (lane == 0) red2[wid] = ss;
    __syncthreads();
    const float var = (red2[0] + red2[1] + red2[2] + red2[3]) * (1.0f / 768.0f);
    const float inv = rsqrtf(var + 1e-5f);
    const float y0 = d0 * inv * g[t] + bb[t];
    const float y1 = d1 * inv * g[t + 256] + bb[t + 256];
    const float y2 = d2 * inv * g[t + 512] + bb[t + 512];
    float* of = outf + (size_t)row * EMBED;
    of[t] = y0; of[t + 256] = y1; of[t + 512] = y2;
    if (SBF) {
        short* ob = outb + (size_t)row * EMBED;
        ob[t] = f2bf(y0); ob[t + 256] = f2bf(y1); ob[t + 512] = f2bf(y2);
    }
}

extern "C" void kernel_launch(void* const* d_in, const int* in_sizes, int n_in,
                              void* d_out, int out_size, void* d_ws, size_t ws_size,
                              hipStream_t stream)
{
    (void)in_sizes; (void)n_in; (void)out_size; (void)ws_size;
    const float* itok = (const float*)d_in[0];
    const float* ptok = (const float*)d_in[1];
    const float* ipos = (const float*)d_in[2];
    const float* ppos = (const float*)d_in[3];
    const float* Wip = (const float*)d_in[4];  const float* bip = (const float*)d_in[5];
    const float* Wpp = (const float*)d_in[6];  const float* bpp = (const float*)d_in[7];
    const float* Wq  = (const float*)d_in[8];  const float* bq  = (const float*)d_in[9];
    const float* Wk  = (const float*)d_in[10]; const float* bk  = (const float*)d_in[11];
    const float* Wv  = (const float*)d_in[12]; const float* bv  = (const float*)d_in[13];
    const float* Wo  = (const float*)d_in[14]; const float* bo  = (const float*)d_in[15];
    const float* g1  = (const float*)d_in[16]; const float* b1  = (const float*)d_in[17];
    const float* g2  = (const float*)d_in[18]; const float* b2  = (const float*)d_in[19];
    const float* Wf1 = (const float*)d_in[20]; const float* bf1 = (const float*)d_in[21];
    const float* Wf2 = (const float*)d_in[22]; const float* bf2 = (const float*)d_in[23];
    float* out = (float*)d_out;

    char* ws = (char*)d_ws;
    constexpr size_t SZ_BF  = (size_t)MROWS * EMBED * 2;   // 12.58 MB
    constexpr size_t SZ_F32 = (size_t)MROWS * EMBED * 4;   // 25.17 MB
    constexpr size_t W768B  = (size_t)EMBED * EMBED * 2;
    constexpr size_t W1536B = (size_t)EMBED * FFDIM * 2;

    size_t o = 0;
    short* v_bf     = (short*)(ws + o); o += SZ_BF;
    short* pt_bf    = (short*)(ws + o); o += SZ_BF;
    short* ip_bf    = (short*)(ws + o); o += SZ_BF;
    short* pp_bf    = (short*)(ws + o); o += SZ_BF;   // reused as vt_bf after gemm3
    short* qin_bf   = (short*)(ws + o); o += SZ_BF;   // qin+kin reused as h_bf
    short* kin_bf   = (short*)(ws + o); o += SZ_BF;
    short* qn_bf    = (short*)(ws + o); o += SZ_BF;
    short* kn_bf    = (short*)(ws + o); o += SZ_BF;
    short* attn_bf  = (short*)(ws + o); o += SZ_BF;
    float* x_f32    = (float*)(ws + o); o += SZ_F32;  // x1 then x2
    short* fused_bf = (short*)(ws + o); o += SZ_BF;
    float* fused_f32= (float*)(ws + o); o += SZ_F32;
    short* wip_t = (short*)(ws + o); o += W768B;
    short* wpp_t = (short*)(ws + o); o += W768B;
    short* wq_t  = (short*)(ws + o); o += W768B;
    short* wk_t  = (short*)(ws + o); o += W768B;
    short* wv_t  = (short*)(ws + o); o += W768B;
    short* wo_t  = (short*)(ws + o); o += W768B;
    short* wf1_t = (short*)(ws + o); o += W1536B;
    short* wf2_t = (short*)(ws + o); o += W1536B;
    short* vt_bf = pp_bf;
    short* h_bf  = qin_bf;  // spans qin+kin (25.17 MB)

    const dim3 blk(256);

    cvt3_kernel<<<dim3(MROWS * EMBED / 1024, 3), blk, 0, stream>>>(
        ptok, ipos, ppos, pt_bf, ip_bf, pp_bf);

    transpose_w<<<dim3(EMBED / 32, EMBED / 32), blk, 0, stream>>>(Wip, wip_t, EMBED, EMBED);
    transpose_w<<<dim3(EMBED / 32, EMBED / 32), blk, 0, stream>>>(Wpp, wpp_t, EMBED, EMBED);
    transpose_w<<<dim3(EMBED / 32, EMBED / 32), blk, 0, stream>>>(Wq,  wq_t,  EMBED, EMBED);
    transpose_w<<<dim3(EMBED / 32, EMBED / 32), blk, 0, stream>>>(Wk,  wk_t,  EMBED, EMBED);
    transpose_w<<<dim3(EMBED / 32, EMBED / 32), blk, 0, stream>>>(Wv,  wv_t,  EMBED, EMBED);
    transpose_w<<<dim3(EMBED / 32, EMBED / 32), blk, 0, stream>>>(Wo,  wo_t,  EMBED, EMBED);
    transpose_w<<<dim3(FFDIM / 32, EMBED / 32), blk, 0, stream>>>(Wf1, wf1_t, EMBED, FFDIM);
    transpose_w<<<dim3(EMBED / 32, FFDIM / 32), blk, 0, stream>>>(Wf2, wf2_t, FFDIM, EMBED);

    // qin = itok + ipos@Wip + bip ; kin = ptok + ppos@Wpp + bpp ; v = ptok@Wv + bv
    gemm3_kernel<<<dim3(6, 64, 3), blk, 0, stream>>>(
        ip_bf, wip_t, bip, itok, qin_bf,
        pp_bf, wpp_t, bpp, ptok, kin_bf,
        pt_bf, wv_t,  bv,  nullptr, v_bf);

    // qn = l2norm(qin@Wq + bq) ; kn = l2norm(kin@Wk + bk)
    gemm2_kernel<<<dim3(6, 64, 2), blk, 0, stream>>>(
        qin_bf, wq_t, bq, qn_bf,
        kin_bf, wk_t, bk, kn_bf);

    transpose_v<<<dim3(SEQ / 64, BATCH * HEADS), blk, 0, stream>>>(v_bf, vt_bf);
    attn_kernel<<<dim3(SEQ / 128, BATCH * HEADS), blk, 0, stream>>>(qn_bf, kn_bf, vt_bf, attn_bf);

    // x1 = itok + attn@Wo + bo
    gemm_bt<0,0,0,1><<<dim3(6, 64), blk, 0, stream>>>(attn_bf, wo_t, bo, itok, nullptr, x_f32, EMBED, EMBED);
    layernorm_768<1><<<dim3(MROWS), blk, 0, stream>>>(x_f32, g1, b1, fused_f32, fused_bf);
    // h = gelu(fused@Wf1 + bf1)
    gemm_bt<0,1,1,0><<<dim3(12, 64), blk, 0, stream>>>(fused_bf, wf1_t, bf1, nullptr, h_bf, nullptr, FFDIM, EMBED);
    // x2 = fused + h@Wf2 + bf2
    gemm_bt<0,0,0,1><<<dim3(6, 64), blk, 0, stream>>>(h_bf, wf2_t, bf2, fused_f32, nullptr, x_f32, EMBED, FFDIM);
    layernorm_768<0><<<dim3(MROWS), blk, 0, stream>>>(x_f32, g2, b2, out, nullptr);
}

// Round 4
// 518.100 us; speedup vs baseline: 1.2362x; 1.0026x over previous
//
#include <hip/hip_runtime.h>

#define EMBED 768
#define FFDIM 1536
#define BATCH 4
#define SEQ   2048
#define HEADS 12
#define MROWS (BATCH*SEQ)   // 8192
#define LOG2E 1.44269504088896340736f

typedef __attribute__((ext_vector_type(4)))  float  f32x4;
typedef __attribute__((ext_vector_type(16))) float  f32x16;
typedef __attribute__((ext_vector_type(8)))  __bf16 bf16x8;
typedef __attribute__((ext_vector_type(4)))  short  s16x4;

__device__ __forceinline__ short f2bf(float f) {
    union { float f; unsigned u; } x; x.f = f;
    unsigned r = x.u + 0x7fffu + ((x.u >> 16) & 1u);
    return (short)(r >> 16);
}
__device__ __forceinline__ float bf2f(short s) {
    union { unsigned u; float f; } x; x.u = ((unsigned)(unsigned short)s) << 16;
    return x.f;
}
__device__ __forceinline__ unsigned cvtpk(float lo, float hi) {
    unsigned r;
    asm("v_cvt_pk_bf16_f32 %0, %1, %2" : "=v"(r) : "v"(lo), "v"(hi));
    return r;
}
__device__ __forceinline__ float exp2a(float x) {   // 2^x
    float r;
    asm("v_exp_f32 %0, %1" : "=v"(r) : "v"(x));
    return r;
}
__device__ __forceinline__ void gll16(const void* g, void* l) {
    __builtin_amdgcn_global_load_lds(
        (const __attribute__((address_space(1))) void*)g,
        (__attribute__((address_space(3))) void*)l, 16, 0, 0);
}
// swizzled read of one 16B chunk from a 64-col (128B-stride) row-major bf16 LDS tile
__device__ __forceinline__ bf16x8 ldsw(const short* base, int row, int chunk) {
    return *(const bf16x8*)((const char*)base + row * 128 + (((chunk ^ (row & 7))) << 4));
}

// ---------------- fp32 -> bf16 convert: 4 token tensors + 2 raw weights ----------------
__global__ __launch_bounds__(256) void cvt6_kernel(
    const float* __restrict__ s0, const float* __restrict__ s1,
    const float* __restrict__ s2, const float* __restrict__ s3,
    const float* __restrict__ w0, const float* __restrict__ w1,
    short* o0, short* o1, short* o2, short* o3, short* ow0, short* ow1)
{
    const float* s; short* o; size_t nelem;
    switch (blockIdx.y) {
        case 0:  s = s0; o = o0; nelem = (size_t)MROWS * EMBED; break;
        case 1:  s = s1; o = o1; nelem = (size_t)MROWS * EMBED; break;
        case 2:  s = s2; o = o2; nelem = (size_t)MROWS * EMBED; break;
        case 3:  s = s3; o = o3; nelem = (size_t)MROWS * EMBED; break;
        case 4:  s = w0; o = ow0; nelem = (size_t)EMBED * EMBED; break;
        default: s = w1; o = ow1; nelem = (size_t)EMBED * EMBED; break;
    }
    size_t i = ((size_t)blockIdx.x * 256 + threadIdx.x) * 4;
    if (i >= nelem) return;
    float4 v = *(const float4*)(s + i);
    s16x4 r;
    r[0] = f2bf(v.x); r[1] = f2bf(v.y); r[2] = f2bf(v.z); r[3] = f2bf(v.w);
    *(s16x4*)(o + i) = r;
}

// ---------------- 6 weight transposes in one dispatch: W[K][N] f32 -> Wt[N][K] bf16 ----------------
__global__ __launch_bounds__(256) void transpose6_kernel(
    const float* Wq, const float* Wk, const float* Wv, const float* Wo_,
    const float* Wf1, const float* Wf2,
    short* wq_t, short* wqcat, short* wk_t, short* wkcat,
    short* wv_t, short* wo_t, short* wf1_t, short* wf2_t)
{
    const float* W; int K, N, st1, st2; short *d1, *d2;
    switch (blockIdx.z) {
        case 0: W = Wq;  K = 768;  N = 768;  d1 = wq_t;  st1 = 768;  d2 = wqcat; st2 = 1536; break;
        case 1: W = Wk;  K = 768;  N = 768;  d1 = wk_t;  st1 = 768;  d2 = wkcat; st2 = 1536; break;
        case 2: W = Wv;  K = 768;  N = 768;  d1 = wv_t;  st1 = 768;  d2 = nullptr; st2 = 0;  break;
        case 3: W = Wo_; K = 768;  N = 768;  d1 = wo_t;  st1 = 768;  d2 = nullptr; st2 = 0;  break;
        case 4: W = Wf1; K = 768;  N = 1536; d1 = wf1_t; st1 = 768;  d2 = nullptr; st2 = 0;  break;
        default:W = Wf2; K = 1536; N = 768;  d1 = wf2_t; st1 = 1536; d2 = nullptr; st2 = 0;  break;
    }
    const int k0 = blockIdx.y * 32, n0 = blockIdx.x * 32;
    if (k0 >= K || n0 >= N) return;
    __shared__ float tile[32][33];
    const int tx = threadIdx.x & 31, ty = threadIdx.x >> 5;  // 32 x 8
    #pragma unroll
    for (int i = 0; i < 32; i += 8)
        tile[ty + i][tx] = W[(size_t)(k0 + ty + i) * N + n0 + tx];
    __syncthreads();
    #pragma unroll
    for (int i = 0; i < 32; i += 8) {
        const short v = f2bf(tile[tx][ty + i]);
        d1[(size_t)(n0 + ty + i) * st1 + k0 + tx] = v;
        if (d2) d2[(size_t)(n0 + ty + i) * st2 + k0 + tx] = v;
    }
}

// ---------------- composed biases: bqc = bq + bip@Wq ; bkc = bk + bpp@Wk ----------------
__global__ __launch_bounds__(256) void biascomp_kernel(
    const float* bip, const float* Wq, const float* bq, float* bqc,
    const float* bpp, const float* Wk, const float* bk, float* bkc)
{
    const float *bi, *W, *bb; float* o;
    if (blockIdx.y) { bi = bpp; W = Wk; bb = bk; o = bkc; }
    else            { bi = bip; W = Wq; bb = bq; o = bqc; }
    const int n = blockIdx.x * 256 + threadIdx.x;
    float acc = bb[n];
    #pragma unroll 16
    for (int j = 0; j < 768; ++j) acc += bi[j] * W[(size_t)j * 768 + n];
    o[n] = acc;
}

// ---------------- GEMM core ----------------
// 128x128 tile, BK=32, 4 waves (2x2), double-buffered LDS, 1 barrier / K-step.
typedef short lds_tile_t[128][32];

template<int DUALA, int L2N, int GELU_, int RESF, int RESB, int SBF, int SF32>
__device__ __forceinline__ void gemm_core(
    lds_tile_t* As, lds_tile_t* Bs,
    const short* __restrict__ A1, const short* __restrict__ A2,
    const short* __restrict__ Wt, const float* __restrict__ bias,
    const float* __restrict__ residf, const short* __restrict__ residb,
    short* __restrict__ outb, float* __restrict__ outf,
    int N, int K, int ostr, float l2scale)
{
    const int tid = threadIdx.x;
    const int mbase = blockIdx.y * 128, nbase = blockIdx.x * 128;
    const int wid = tid >> 6, lane = tid & 63;
    const int wm = wid >> 1, wn = wid & 1;
    const int l15 = lane & 15, lhi = lane >> 4;
    const int sr = tid >> 2;         // 0..63
    const int sc = (tid & 3) * 8;    // 0/8/16/24

    f32x4 acc[4][4] = {};
    const short* Bb = Wt + (size_t)nbase * K;

#define GSTAGE(buf, kk) do {                                                        \
    if (DUALA) {                                                                    \
        const short* ab = ((kk) < 768 ? A1 : A2) + (size_t)mbase * 768;             \
        const int ko = (kk) & 767;                                                  \
        gll16(ab + (size_t)sr * 768        + ko + sc, &As[buf][sr][sc]);            \
        gll16(ab + (size_t)(64 + sr) * 768 + ko + sc, &As[buf][64 + sr][sc]);       \
    } else {                                                                        \
        const short* ab = A1 + (size_t)mbase * K;                                   \
        gll16(ab + (size_t)sr * K        + (kk) + sc, &As[buf][sr][sc]);            \
        gll16(ab + (size_t)(64 + sr) * K + (kk) + sc, &As[buf][64 + sr][sc]);       \
    }                                                                               \
    gll16(Bb + (size_t)sr * K        + (kk) + sc, &Bs[buf][sr][sc]);                \
    gll16(Bb + (size_t)(64 + sr) * K + (kk) + sc, &Bs[buf][64 + sr][sc]);           \
} while (0)

    GSTAGE(0, 0);
    __syncthreads();

    const int nk = K >> 5;
    for (int t = 0; t < nk; ++t) {
        const int cur = t & 1;
        if (t + 1 < nk) { GSTAGE(cur ^ 1, (t + 1) << 5); }
        bf16x8 av[4], bv[4];
        #pragma unroll
        for (int tt = 0; tt < 4; ++tt) {
            av[tt] = *(const bf16x8*)(&As[cur][wm * 64 + tt * 16 + l15][lhi * 8]);
            bv[tt] = *(const bf16x8*)(&Bs[cur][wn * 64 + tt * 16 + l15][lhi * 8]);
        }
        #pragma unroll
        for (int mt = 0; mt < 4; ++mt)
            #pragma unroll
            for (int nt = 0; nt < 4; ++nt)
                acc[mt][nt] = __builtin_amdgcn_mfma_f32_16x16x32_bf16(
                    av[mt], bv[nt], acc[mt][nt], 0, 0, 0);
        __syncthreads();
    }
#undef GSTAGE

    #pragma unroll
    for (int mt = 0; mt < 4; ++mt) {
        float vals[4][4];
        #pragma unroll
        for (int nt = 0; nt < 4; ++nt) {
            const int col = nbase + wn * 64 + nt * 16 + l15;
            const float bc = bias ? bias[col] : 0.f;
            #pragma unroll
            for (int j = 0; j < 4; ++j) vals[nt][j] = acc[mt][nt][j] + bc;
        }
        if (RESF || RESB) {
            #pragma unroll
            for (int nt = 0; nt < 4; ++nt) {
                const int col = nbase + wn * 64 + nt * 16 + l15;
                #pragma unroll
                for (int j = 0; j < 4; ++j) {
                    const int row = mbase + wm * 64 + mt * 16 + lhi * 4 + j;
                    if (RESF) vals[nt][j] += residf[(size_t)row * N + col];
                    if (RESB) vals[nt][j] += bf2f(residb[(size_t)row * N + col]);
                }
            }
        }
        if (L2N) {  // l2-normalize over this wave's 64-col head span, then scale
            #pragma unroll
            for (int j = 0; j < 4; ++j) {
                float s = 0.f;
                #pragma unroll
                for (int nt = 0; nt < 4; ++nt) s += vals[nt][j] * vals[nt][j];
                s += __shfl_xor(s, 1); s += __shfl_xor(s, 2);
                s += __shfl_xor(s, 4); s += __shfl_xor(s, 8);
                const float inv = l2scale / fmaxf(sqrtf(s), 1e-12f);
                #pragma unroll
                for (int nt = 0; nt < 4; ++nt) vals[nt][j] *= inv;
            }
        }
        if (GELU_) {
            #pragma unroll
            for (int nt = 0; nt < 4; ++nt)
                #pragma unroll
                for (int j = 0; j < 4; ++j) {
                    const float v = vals[nt][j];
                    vals[nt][j] = 0.5f * v * (1.0f + erff(v * 0.70710678118654752f));
                }
        }
        #pragma unroll
        for (int nt = 0; nt < 4; ++nt) {
            const int col = nbase + wn * 64 + nt * 16 + l15;
            #pragma unroll
            for (int j = 0; j < 4; ++j) {
                const int row = mbase + wm * 64 + mt * 16 + lhi * 4 + j;
                if (SBF)  outb[(size_t)row * ostr + col] = f2bf(vals[nt][j]);
                if (SF32) outf[(size_t)row * ostr + col] = vals[nt][j];
            }
        }
    }
}

// weight composition: wqcat[:,768:] = (Wip@Wq)^T ; wkcat[:,768:] = (Wpp@Wk)^T
__global__ __launch_bounds__(256) void compose_kernel(
    const short* wq_t, const short* wip_bf, short* wqcat,
    const short* wk_t, const short* wpp_bf, short* wkcat)
{
    __shared__ lds_tile_t As[2], Bs[2];
    const short *A, *W; short* o;
    if (blockIdx.z == 0) { A = wq_t; W = wip_bf; o = wqcat + 768; }
    else                 { A = wk_t; W = wpp_bf; o = wkcat + 768; }
    gemm_core<0,0,0,0,0,1,0>(As, Bs, A, nullptr, W, nullptr, nullptr, nullptr,
                             o, nullptr, 768, 768, 1536, 1.f);
}

// QKV mega-dispatch: z=0 q (dual-A K=1536, l2n*log2e), z=1 k (dual-A, l2n), z=2 v (K=768)
__global__ __launch_bounds__(256) void qkv_kernel(
    const short* itok_bf, const short* ipos_bf, const short* wqcat, const float* bqc, short* qn,
    const short* ptok_bf, const short* ppos_bf, const short* wkcat, const float* bkc, short* kn,
    const short* wv_t, const float* bv, short* v_bf)
{
    __shared__ lds_tile_t As[2], Bs[2];
    const int z = blockIdx.z;
    if (z == 2) {
        gemm_core<0,0,0,0,0,1,0>(As, Bs, ptok_bf, nullptr, wv_t, bv, nullptr, nullptr,
                                 v_bf, nullptr, 768, 768, 768, 1.f);
    } else {
        const short* a1 = z ? ptok_bf : itok_bf;
        const short* a2 = z ? ppos_bf : ipos_bf;
        const short* w  = z ? wkcat   : wqcat;
        const float* bi = z ? bkc     : bqc;
        short* o        = z ? kn      : qn;
        gemm_core<1,1,0,0,0,1,0>(As, Bs, a1, a2, w, bi, nullptr, nullptr,
                                 o, nullptr, 768, 1536, 768, z ? 1.f : LOG2E);
    }
}

// x1 = itok + attn@Wo + bo  (bf16 out)
__global__ __launch_bounds__(256) void wo_kernel(
    const short* attn_bf, const short* wo_t, const float* bo, const float* itok, short* x1_bf)
{
    __shared__ lds_tile_t As[2], Bs[2];
    gemm_core<0,0,0,1,0,1,0>(As, Bs, attn_bf, nullptr, wo_t, bo, itok, nullptr,
                             x1_bf, nullptr, 768, 768, 768, 1.f);
}

// h = gelu(fused@Wf1 + bf1)
__global__ __launch_bounds__(256) void wf1_kernel(
    const short* fused_bf, const short* wf1_t, const float* bf1, short* h_bf)
{
    __shared__ lds_tile_t As[2], Bs[2];
    gemm_core<0,0,1,0,0,1,0>(As, Bs, fused_bf, nullptr, wf1_t, bf1, nullptr, nullptr,
                             h_bf, nullptr, 1536, 768, 1536, 1.f);
}

// x2 = fused + h@Wf2 + bf2  (bf16 out)
__global__ __launch_bounds__(256) void wf2_kernel(
    const short* h_bf, const short* wf2_t, const float* bf2, const short* fused_bf, short* x2_bf)
{
    __shared__ lds_tile_t As[2], Bs[2];
    gemm_core<0,0,0,0,1,1,0>(As, Bs, h_bf, nullptr, wf2_t, bf2, nullptr, fused_bf,
                             x2_bf, nullptr, 768, 1536, 768, 1.f);
}

// ---------------- v [B*SEQ][768] bf16 -> vt [B][H][64][SEQ] bf16 ----------------
__global__ __launch_bounds__(256) void transpose_v(
    const short* __restrict__ v, short* __restrict__ vt)
{
    __shared__ short tile[64][65];
    const int bh = blockIdx.y;
    const int b = bh / HEADS, h = bh % HEADS;
    const int k0 = blockIdx.x * 64;
    const int tx = threadIdx.x & 63, ty = threadIdx.x >> 6;  // 64 x 4
    #pragma unroll
    for (int i = 0; i < 64; i += 4)
        tile[ty + i][tx] = v[(size_t)(b * SEQ + k0 + ty + i) * EMBED + h * 64 + tx];
    __syncthreads();
    #pragma unroll
    for (int i = 0; i < 64; i += 4)
        vt[(size_t)(bh * 64 + ty + i) * SEQ + k0 + tx] = tile[tx][ty + i];
}

// ---------------- attention: 32x32x16 MFMA, in-register P, exp2 + permlane ----------------
// 4 waves x 32 q = 128 q/block; K/V double-buffered + swizzled; qn pre-scaled by log2e.
__global__ __launch_bounds__(256) void attn_kernel(
    const short* __restrict__ qn, const short* __restrict__ kn,
    const short* __restrict__ vt, short* __restrict__ outp)
{
    __shared__ short Ks[2][64][64];    // 16 KB (reused as O-transpose buffer at end)
    __shared__ short Vs[2][64][64];    // 16 KB; Vs[d][k]

    const int bh = blockIdx.y;
    const int b = bh / HEADS, h = bh % HEADS;
    const int q0 = blockIdx.x * 128;
    const int tid = threadIdx.x, wq = tid >> 6, lane = tid & 63;
    const int l31 = lane & 31, hi = lane >> 5;
    const int srow = tid >> 3;        // 0..31 (staging row within half-tile)
    const int schk = tid & 7;         // 0..7  (staging chunk)

    // Q as B-fragments in registers (pre-scaled by log2e at projection)
    const size_t qrow = (size_t)(b * SEQ + q0 + wq * 32 + l31) * EMBED + h * 64;
    bf16x8 qf[4];
    #pragma unroll
    for (int t = 0; t < 4; ++t)
        qf[t] = *(const bf16x8*)(qn + qrow + t * 16 + hi * 8);

    const short* kbase = kn + (size_t)b * SEQ * EMBED + h * 64;
    const short* vbase = vt + (size_t)bh * 64 * SEQ;

#define ASTAGE(buf, k0x) do {                                                            \
    _Pragma("unroll")                                                                    \
    for (int rr = 0; rr < 2; ++rr) {                                                     \
        const int row = rr * 32 + srow;                                                  \
        gll16(kbase + (size_t)((k0x) + row) * EMBED + ((schk ^ (row & 7)) * 8),          \
              &Ks[buf][row][schk * 8]);                                                  \
        gll16(vbase + (size_t)row * SEQ + (k0x) + ((schk ^ (row & 7)) * 8),              \
              &Vs[buf][row][schk * 8]);                                                  \
    }                                                                                    \
} while (0)

    ASTAGE(0, 0);
    __syncthreads();

    f32x16 acc_o[2] = {};
    float rsum = 0.f;
    const int NT = SEQ / 64;

    for (int kt = 0; kt < NT; ++kt) {
        const int cur = kt & 1;
        if (kt + 1 < NT) { ASTAGE(cur ^ 1, (kt + 1) * 64); }

        // S^T = mfma(K, Q): lane holds S^T[k][q=l31]; k = kb*32 + (reg&3)+8*(reg>>2)+4*hi
        f32x16 s0 = {}, s1 = {};
        #pragma unroll
        for (int t = 0; t < 4; ++t) {
            bf16x8 kf0 = ldsw(&Ks[cur][0][0], l31,      t * 2 + hi);
            bf16x8 kf1 = ldsw(&Ks[cur][0][0], 32 + l31, t * 2 + hi);
            s0 = __builtin_amdgcn_mfma_f32_32x32x16_bf16(kf0, qf[t], s0, 0, 0, 0);
            s1 = __builtin_amdgcn_mfma_f32_32x32x16_bf16(kf1, qf[t], s1, 0, 0, 0);
        }

        // P = exp2(S) (qn carries the log2e factor); scores bounded -> no max-tracking
        float e0[16], e1[16];
        #pragma unroll
        for (int i = 0; i < 16; ++i) { const float e = exp2a(s0[i]); rsum += e; e0[i] = e; }
        #pragma unroll
        for (int i = 0; i < 16; ++i) { const float e = exp2a(s1[i]); rsum += e; e1[i] = e; }

        // pack to bf16 words: w[kb][2a+t] covers k-pair kb*32 + 8a + 4*hi + 2t
        unsigned w[2][8];
        #pragma unroll
        for (int a = 0; a < 4; ++a) {
            w[0][2*a]   = cvtpk(e0[4*a],   e0[4*a+1]);
            w[0][2*a+1] = cvtpk(e0[4*a+2], e0[4*a+3]);
            w[1][2*a]   = cvtpk(e1[4*a],   e1[4*a+1]);
            w[1][2*a+1] = cvtpk(e1[4*a+2], e1[4*a+3]);
        }

        // O^T += mfma(V^T, P^T): build B-frags with 2 permlane32_swap per (kb,ks)
        #pragma unroll
        for (int kb = 0; kb < 2; ++kb) {
            #pragma unroll
            for (int ks = 0; ks < 2; ++ks) {
                unsigned p0 = w[kb][4*ks], p1 = w[kb][4*ks+1];
                unsigned p2 = w[kb][4*ks+2], p3 = w[kb][4*ks+3];
                asm("v_permlane32_swap_b32 %0, %1" : "+v"(p0), "+v"(p2));
                asm("v_permlane32_swap_b32 %0, %1" : "+v"(p1), "+v"(p3));
                union { unsigned u[4]; bf16x8 v; } pf;
                pf.u[0] = p0; pf.u[1] = p1; pf.u[2] = p2; pf.u[3] = p3;
                #pragma unroll
                for (int db = 0; db < 2; ++db) {
                    bf16x8 vf = ldsw(&Vs[cur][0][0], db * 32 + l31, kb * 4 + ks * 2 + hi);
                    acc_o[db] = __builtin_amdgcn_mfma_f32_32x32x16_bf16(vf, pf.v, acc_o[db], 0, 0, 0);
                }
            }
        }
        __syncthreads();  // drains vmcnt (prefetch) + protects buffer swap
    }
#undef ASTAGE

    // softmax denominator: k-subsets split across lane pairs l, l^32
    const float rtot = rsum + __shfl_xor(rsum, 32);
    const float rinv = 1.0f / rtot;

    // O^T -> LDS (swizzled) -> coalesced global store. Reuse Ks region.
    short* Osb = &Ks[0][0][0];
    const int ql = wq * 32 + l31;
    #pragma unroll
    for (int db = 0; db < 2; ++db)
        #pragma unroll
        for (int a = 0; a < 4; ++a) {
            const float v0 = acc_o[db][4*a]   * rinv, v1 = acc_o[db][4*a+1] * rinv;
            const float v2 = acc_o[db][4*a+2] * rinv, v3 = acc_o[db][4*a+3] * rinv;
            uint2 pw; pw.x = cvtpk(v0, v1); pw.y = cvtpk(v2, v3);
            const int byteoff = ql * 128 + (((db * 4 + a) ^ (ql & 7)) << 4) + hi * 8;
            *(uint2*)((char*)Osb + byteoff) = pw;
        }
    __syncthreads();
    #pragma unroll
    for (int p = 0; p < 2; ++p) {
        const int r = p * 64 + (tid >> 2);
        #pragma unroll
        for (int i = 0; i < 2; ++i) {
            const int c = (tid & 3) * 2 + i;
            bf16x8 v = ldsw(Osb, r, c);
            *(bf16x8*)(outp + (size_t)(b * SEQ + q0 + r) * EMBED + h * 64 + c * 8) = v;
        }
    }
}

// ---------------- layernorm over 768 cols, bf16 input ----------------
template<int OUTBF>
__global__ __launch_bounds__(256) void layernorm_768(
    const short* __restrict__ x, const float* __restrict__ g, const float* __restrict__ bb,
    float* __restrict__ outf, short* __restrict__ outb)
{
    const int row = blockIdx.x;
    const short* xr = x + (size_t)row * EMBED;
    const int t = threadIdx.x;
    const float v0 = bf2f(xr[t]), v1 = bf2f(xr[t + 256]), v2 = bf2f(xr[t + 512]);
    float s = v0 + v1 + v2;
    #pragma unroll
    for (int m = 1; m < 64; m <<= 1) s += __shfl_xor(s, m);
    __shared__ float red[4];
    __shared__ float red2[4];
    const int wid = t >> 6, lane = t & 63;
    if (lane == 0) red[wid] = s;
    __syncthreads();
    const float mu = (red[0] + red[1] + red[2] + red[3]) * (1.0f / 768.0f);
    const float d0 = v0 - mu, d1 = v1 - mu, d2 = v2 - mu;
    float ss = d0 * d0 + d1 * d1 + d2 * d2;
    #pragma unroll
    for (int m = 1; m < 64; m <<= 1) ss += __shfl_xor(ss, m);
    if (lane == 0) red2[wid] = ss;
    __syncthreads();
    const float var = (red2[0] + red2[1] + red2[2] + red2[3]) * (1.0f / 768.0f);
    const float inv = rsqrtf(var + 1e-5f);
    const float y0 = d0 * inv * g[t] + bb[t];
    const float y1 = d1 * inv * g[t + 256] + bb[t + 256];
    const float y2 = d2 * inv * g[t + 512] + bb[t + 512];
    if (OUTBF) {
        short* ob = outb + (size_t)row * EMBED;
        ob[t] = f2bf(y0); ob[t + 256] = f2bf(y1); ob[t + 512] = f2bf(y2);
    } else {
        float* of = outf + (size_t)row * EMBED;
        of[t] = y0; of[t + 256] = y1; of[t + 512] = y2;
    }
}

extern "C" void kernel_launch(void* const* d_in, const int* in_sizes, int n_in,
                              void* d_out, int out_size, void* d_ws, size_t ws_size,
                              hipStream_t stream)
{
    (void)in_sizes; (void)n_in; (void)out_size; (void)ws_size;
    const float* itok = (const float*)d_in[0];
    const float* ptok = (const float*)d_in[1];
    const float* ipos = (const float*)d_in[2];
    const float* ppos = (const float*)d_in[3];
    const float* Wip = (const float*)d_in[4];  const float* bip = (const float*)d_in[5];
    const float* Wpp = (const float*)d_in[6];  const float* bpp = (const float*)d_in[7];
    const float* Wq  = (const float*)d_in[8];  const float* bq  = (const float*)d_in[9];
    const float* Wk  = (const float*)d_in[10]; const float* bk  = (const float*)d_in[11];
    const float* Wv  = (const float*)d_in[12]; const float* bv  = (const float*)d_in[13];
    const float* Wo  = (const float*)d_in[14]; const float* bo  = (const float*)d_in[15];
    const float* g1  = (const float*)d_in[16]; const float* b1  = (const float*)d_in[17];
    const float* g2  = (const float*)d_in[18]; const float* b2  = (const float*)d_in[19];
    const float* Wf1 = (const float*)d_in[20]; const float* bf1 = (const float*)d_in[21];
    const float* Wf2 = (const float*)d_in[22]; const float* bf2 = (const float*)d_in[23];
    float* out = (float*)d_out;

    char* ws = (char*)d_ws;
    constexpr size_t SZ_BF  = (size_t)MROWS * EMBED * 2;    // 12.58 MB
    constexpr size_t W768B  = (size_t)EMBED * EMBED * 2;    // 1.18 MB
    constexpr size_t W1536B = (size_t)EMBED * FFDIM * 2;    // 2.36 MB

    size_t o = 0;
    short* itok_bf = (short*)(ws + o); o += SZ_BF;
    short* ptok_bf = (short*)(ws + o); o += SZ_BF;
    short* ipos_bf = (short*)(ws + o); o += SZ_BF;
    short* ppos_bf = (short*)(ws + o); o += SZ_BF;
    short* qn_bf   = (short*)(ws + o); o += SZ_BF;
    short* kn_bf   = (short*)(ws + o); o += SZ_BF;
    short* v_bf    = (short*)(ws + o); o += SZ_BF;
    short* vt_bf   = (short*)(ws + o); o += SZ_BF;
    short* attn_bf = (short*)(ws + o); o += SZ_BF;
    short* x1_bf   = (short*)(ws + o); o += SZ_BF;
    short* fused_bf= (short*)(ws + o); o += SZ_BF;
    short* h_bf    = (short*)(ws + o); o += 2 * SZ_BF;     // 8192 x 1536
    short* x2_bf   = (short*)(ws + o); o += SZ_BF;
    short* wip_bf  = (short*)(ws + o); o += W768B;
    short* wpp_bf  = (short*)(ws + o); o += W768B;
    short* wq_t    = (short*)(ws + o); o += W768B;
    short* wk_t    = (short*)(ws + o); o += W768B;
    short* wv_t    = (short*)(ws + o); o += W768B;
    short* wo_t    = (short*)(ws + o); o += W768B;
    short* wf1_t   = (short*)(ws + o); o += W1536B;
    short* wf2_t   = (short*)(ws + o); o += W1536B;
    short* wqcat   = (short*)(ws + o); o += W1536B;        // [768][1536]
    short* wkcat   = (short*)(ws + o); o += W1536B;
    float* bqc     = (float*)(ws + o); o += 768 * 4;
    float* bkc     = (float*)(ws + o); o += 768 * 4;

    const dim3 blk(256);

    cvt6_kernel<<<dim3(MROWS * EMBED / 1024, 6), blk, 0, stream>>>(
        itok, ptok, ipos, ppos, Wip, Wpp,
        itok_bf, ptok_bf, ipos_bf, ppos_bf, wip_bf, wpp_bf);

    transpose6_kernel<<<dim3(48, 48, 6), blk, 0, stream>>>(
        Wq, Wk, Wv, Wo, Wf1, Wf2,
        wq_t, wqcat, wk_t, wkcat, wv_t, wo_t, wf1_t, wf2_t);

    biascomp_kernel<<<dim3(3, 2), blk, 0, stream>>>(
        bip, Wq, bq, bqc, bpp, Wk, bk, bkc);

    compose_kernel<<<dim3(6, 6, 2), blk, 0, stream>>>(
        wq_t, wip_bf, wqcat, wk_t, wpp_bf, wkcat);

    qkv_kernel<<<dim3(6, 64, 3), blk, 0, stream>>>(
        itok_bf, ipos_bf, wqcat, bqc, qn_bf,
        ptok_bf, ppos_bf, wkcat, bkc, kn_bf,
        wv_t, bv, v_bf);

    transpose_v<<<dim3(SEQ / 64, BATCH * HEADS), blk, 0, stream>>>(v_bf, vt_bf);
    attn_kernel<<<dim3(SEQ / 128, BATCH * HEADS), blk, 0, stream>>>(qn_bf, kn_bf, vt_bf, attn_bf);

    wo_kernel<<<dim3(6, 64), blk, 0, stream>>>(attn_bf, wo_t, bo, itok, x1_bf);
    layernorm_768<1><<<dim3(MROWS), blk, 0, stream>>>(x1_bf, g1, b1, nullptr, fused_bf);
    wf1_kernel<<<dim3(12, 64), blk, 0, stream>>>(fused_bf, wf1_t, bf1, h_bf);
    wf2_kernel<<<dim3(6, 64), blk, 0, stream>>>(h_bf, wf2_t, bf2, fused_bf, x2_bf);
    layernorm_768<0><<<dim3(MROWS), blk, 0, stream>>>(x2_bf, g2, b2, out, nullptr);
}